// Round 1
// 306.015 us; speedup vs baseline: 1.3352x; 1.3352x over previous
//
#include <hip/hip_runtime.h>
#include <hip/hip_bf16.h>

// SelfMaskedAttention (Transformer-XL rel-pos), B=8 T=512 D=768 H=12 DH=64.
// R11: restructured attention. GEMM<0>/<1> epilogues additionally emit bf16
// shadow copies in MFMA-ready layouts (k_ws [t][d], v_ws [d][t], projb), so
// attn staging is pure vectorized short8 copies (no f2b, no scatter, 2-way
// banks). Attention: 64-row t-tile per block, one 16-row sub-tile per wave
// (waves no longer duplicate work), Rl/esl wave-private -> 2 barriers/s-tile.

#define NT 512
#define ND 768
#define NH 12

typedef short short4_t __attribute__((ext_vector_type(4)));
typedef short short8_t __attribute__((ext_vector_type(8)));
typedef float float4_t __attribute__((ext_vector_type(4)));

__device__ __forceinline__ float b2f(unsigned short u) {
    union { unsigned int i; float f; } x; x.i = ((unsigned int)u) << 16; return x.f;
}
__device__ __forceinline__ unsigned short f2b(float f) {
    union { float f; unsigned int i; } x; x.f = f;
    unsigned int i = x.i;
    i += 0x7fffu + ((i >> 16) & 1u);   // RNE
    return (unsigned short)(i >> 16);
}

// ---------------- MFMA GEMM (R10 body; epilogue adds bf16 shadows) ----------------
template <int MODE>
__global__ __launch_bounds__(256) void gemm_mfma(
    const float* __restrict__ Af, const unsigned short* __restrict__ Ab,
    const float* __restrict__ Bw, const float* __restrict__ biasf,
    unsigned short* __restrict__ ob0, float* __restrict__ o1, float* __restrict__ o2,
    unsigned short* __restrict__ sh1, unsigned short* __restrict__ sh2,
    int N, int K, int ldb)
{
    __shared__ unsigned short Al[64][40];
    __shared__ unsigned short Bl[64][40];

    const int tid  = threadIdx.x;
    const int m0   = blockIdx.y * 64;
    const int n0   = blockIdx.x * 64;
    const int wave = tid >> 6;
    const int lane = tid & 63;
    const int lm   = lane & 15;
    const int quad = lane >> 4;
    const int koff = quad * 8;

    float4_t acc[4];
#pragma unroll
    for (int j = 0; j < 4; ++j)
#pragma unroll
        for (int r = 0; r < 4; ++r) acc[j][r] = 0.0f;

    const int arow = tid >> 2;
    const int acg  = (tid & 3) * 8;
    const int bk   = tid & 31;
    const int bg   = tid >> 5;

    for (int k0 = 0; k0 < K; k0 += 32) {
        if (MODE == 2) {
            short8_t av = *(const short8_t*)&Ab[(size_t)(m0 + arow) * K + k0 + acg];
            *(short8_t*)&Al[arow][acg] = av;
        } else {
            const float* src = &Af[(size_t)(m0 + arow) * K + k0 + acg];
            float4_t f0 = *(const float4_t*)src;
            float4_t f1 = *(const float4_t*)(src + 4);
            union { short8_t v; unsigned short u[8]; } pk;
            pk.u[0] = f2b(f0[0]); pk.u[1] = f2b(f0[1]); pk.u[2] = f2b(f0[2]); pk.u[3] = f2b(f0[3]);
            pk.u[4] = f2b(f1[0]); pk.u[5] = f2b(f1[1]); pk.u[6] = f2b(f1[2]); pk.u[7] = f2b(f1[3]);
            *(short8_t*)&Al[arow][acg] = pk.v;
        }
        {
            const float* src = &Bw[(size_t)(k0 + bk) * ldb + n0 + bg * 8];
            float4_t f0 = *(const float4_t*)src;
            float4_t f1 = *(const float4_t*)(src + 4);
            Bl[bg * 8 + 0][bk] = f2b(f0[0]); Bl[bg * 8 + 1][bk] = f2b(f0[1]);
            Bl[bg * 8 + 2][bk] = f2b(f0[2]); Bl[bg * 8 + 3][bk] = f2b(f0[3]);
            Bl[bg * 8 + 4][bk] = f2b(f1[0]); Bl[bg * 8 + 5][bk] = f2b(f1[1]);
            Bl[bg * 8 + 6][bk] = f2b(f1[2]); Bl[bg * 8 + 7][bk] = f2b(f1[3]);
        }
        __syncthreads();

        short8_t af = *(const short8_t*)&Al[wave * 16 + lm][koff];
#pragma unroll
        for (int j = 0; j < 4; ++j) {
            short8_t bf = *(const short8_t*)&Bl[j * 16 + lm][koff];
            acc[j] = __builtin_amdgcn_mfma_f32_16x16x32_bf16(af, bf, acc[j], 0, 0, 0);
        }
        __syncthreads();
    }

#pragma unroll
    for (int j = 0; j < 4; ++j) {
        const int gcol = n0 + j * 16 + lm;
        const float bv = biasf[gcol];
#pragma unroll
        for (int r = 0; r < 4; ++r) {
            const int grow = m0 + wave * 16 + quad * 4 + r;
            const float val = acc[j][r] + bv;
            if (MODE == 0) {
                int b = grow >> 9, t = grow & 511;
                int sec = gcol / 768;
                int cc = gcol - sec * 768;
                int h = cc >> 6, d = cc & 63;
                if (sec == 0) {
                    ob0[((size_t)((b * NH + h) * NT + t)) * 64 + d] = f2b(val);
                } else if (sec == 1) {
                    o1[((size_t)((b * NH + h) * 64 + d)) * NT + t] = val;
                    sh1[((size_t)((b * NH + h) * NT + t)) * 64 + d] = f2b(val);
                } else {
                    o2[((size_t)((b * NH + h) * NT + t)) * 64 + d] = val;
                    sh2[((size_t)((b * NH + h) * 64 + d)) * NT + t] = f2b(val);
                }
            } else if (MODE == 1) {
                int h = gcol >> 6, d = gcol & 63;
                ob0[((size_t)(h * NT + grow)) * 64 + d] = f2b(val);   // projb bf16
            } else {
                o1[(size_t)grow * ND + gcol] = val;
            }
        }
    }
}

// ---------------- bias_cp (reads bf16 projb now) ----------------
__global__ __launch_bounds__(256) void biascp_kernel(
    const float* __restrict__ rcb, const float* __restrict__ rpb,
    const unsigned short* __restrict__ projb, float* __restrict__ biascp)
{
    __shared__ float cb[64];
    const int h = blockIdx.x;
    const int tid = threadIdx.x;
    if (tid < 64) cb[tid] = rcb[h * 64 + tid] + rpb[h * 64 + tid];
    __syncthreads();
    for (int p = tid; p < NT; p += 256) {
        const unsigned short* pr = &projb[((size_t)(h * NT + p)) * 64];
        float s = 0.f;
#pragma unroll 8
        for (int d = 0; d < 64; ++d) s += b2f(pr[d]) * cb[d];
        biascp[h * NT + p] = s;
    }
}

// ---------------- MFMA attention: grid (8, 96), 256 thr, 64-row t-tile ----------
// Wave w owns t-rows [t0+16w, t0+16w+15]. Per s-tile (64 cols): vectorized bf16
// staging of K^T/V^T/proj-window (2 barriers), then per-wave QK^T (<=8 mfma),
// R = Q.proj^T with bias folded (<=10 mfma), e = exp(.)*mask, P.V (8 mfma).
// Rl/esl are wave-private LDS slices -> no barrier between their write & read
// (same-wave LDS is in-order; compiler fence keeps program order).
__global__ __launch_bounds__(256) void attn_mfma(
    const unsigned short* __restrict__ q_ws, const unsigned short* __restrict__ k_ws,
    const unsigned short* __restrict__ v_ws, const unsigned short* __restrict__ projb,
    const float* __restrict__ biascp, unsigned short* __restrict__ ctxT)
{
    __shared__ unsigned short Kt[64][72];    // [s][d] bf16
    __shared__ unsigned short Vt[64][72];    // [d][s] bf16
    __shared__ unsigned short pP[128][72];   // [p][d] bf16 (block rel-window)
    __shared__ float          Rl[4][16][84]; // per-wave R + bias, f32
    __shared__ unsigned short esl[4][16][72];// per-wave e bf16 (PV A-operand)

    const int tid  = threadIdx.x;
    const int y    = blockIdx.y;        // b*H + h
    const int h    = y % NH;
    const int b    = y / NH;
    const int t0   = blockIdx.x * 64;
    const int wave = tid >> 6;
    const int lane = tid & 63;
    const int lm   = lane & 15;
    const int quad = lane >> 4;
    const int koff = quad * 8;
    const int tw0  = t0 + wave * 16;
    const int nst  = (t0 >> 6) + 1;

    // Q fragment straight from global (bf16 [t][d]) — no LDS round-trip
    short8_t aq[2];
    aq[0] = *(const short8_t*)&q_ws[((size_t)(y * NT + tw0 + lm)) * 64 + koff];
    aq[1] = *(const short8_t*)&q_ws[((size_t)(y * NT + tw0 + lm)) * 64 + koff + 32];

    float4_t ctxacc[4];
#pragma unroll
    for (int j = 0; j < 4; ++j)
#pragma unroll
        for (int r = 0; r < 4; ++r) ctxacc[j][r] = 0.f;
    float esum[4] = {0.f, 0.f, 0.f, 0.f};

    const int sr = tid >> 2;           // staging row 0..63
    const int sc = (tid & 3) * 16;     // 16-short chunk
    const int pr = tid >> 1;           // proj row 0..127
    const int pc = (tid & 1) * 32;     // 32-short chunk

    for (int st = 0; st < nst; ++st) {
        const int s0      = st * 64;
        const int plo_blk = max(0, t0 - s0 - 63);
        const int cnt_blk = t0 + 63 - s0 - plo_blk + 1;   // 64..127
        if (st) __syncthreads();
        {   // ---- stage K^T [s][d], V^T [d][s], proj window — all short8 copies
            const unsigned short* ks = &k_ws[((size_t)(y * NT + s0 + sr)) * 64 + sc];
            *(short8_t*)&Kt[sr][sc]     = *(const short8_t*)ks;
            *(short8_t*)&Kt[sr][sc + 8] = *(const short8_t*)(ks + 8);
            const unsigned short* vs = &v_ws[((size_t)(y * 64 + sr)) * NT + s0 + sc];
            *(short8_t*)&Vt[sr][sc]     = *(const short8_t*)vs;
            *(short8_t*)&Vt[sr][sc + 8] = *(const short8_t*)(vs + 8);
            if (pr < cnt_blk) {
                const unsigned short* ps = &projb[((size_t)(h * NT + plo_blk + pr)) * 64 + pc];
                *(short8_t*)&pP[pr][pc]      = *(const short8_t*)ps;
                *(short8_t*)&pP[pr][pc + 8]  = *(const short8_t*)(ps + 8);
                *(short8_t*)&pP[pr][pc + 16] = *(const short8_t*)(ps + 16);
                *(short8_t*)&pP[pr][pc + 24] = *(const short8_t*)(ps + 24);
            }
            // rows >= cnt_blk: only pP[127] can be read stale (wave3, j=4) and it
            // feeds exclusively R column p=79, which is never gathered.
        }
        __syncthreads();

        if (s0 <= tw0 + 15) {   // wave-uniform: this wave has active s in tile
            const int plo_w = max(0, tw0 - s0 - 63);
            const int pbase = plo_w - plo_blk;            // always multiple of 16
            const int cntw  = tw0 + 15 - s0 - plo_w + 1;  // 16..79
            const int jmax  = min(3, (tw0 + 15 - s0) >> 4);
            const int jpmax = (cntw - 1) >> 4;            // <= 4

            // ---- QK^T
            float4_t accQK[4];
#pragma unroll
            for (int j = 0; j < 4; ++j)
#pragma unroll
                for (int r = 0; r < 4; ++r) accQK[j][r] = 0.f;
            for (int j = 0; j <= jmax; ++j) {
                short8_t bk0 = *(const short8_t*)&Kt[j * 16 + lm][koff];
                short8_t bk1 = *(const short8_t*)&Kt[j * 16 + lm][koff + 32];
                accQK[j] = __builtin_amdgcn_mfma_f32_16x16x32_bf16(aq[0], bk0, accQK[j], 0, 0, 0);
                accQK[j] = __builtin_amdgcn_mfma_f32_16x16x32_bf16(aq[1], bk1, accQK[j], 0, 0, 0);
            }
            // ---- R = Q . proj^T, bias folded at write
            for (int j = 0; j <= jpmax; ++j) {
                short8_t bp0 = *(const short8_t*)&pP[pbase + j * 16 + lm][koff];
                short8_t bp1 = *(const short8_t*)&pP[pbase + j * 16 + lm][koff + 32];
                float4_t accR;
#pragma unroll
                for (int r = 0; r < 4; ++r) accR[r] = 0.f;
                accR = __builtin_amdgcn_mfma_f32_16x16x32_bf16(aq[0], bp0, accR, 0, 0, 0);
                accR = __builtin_amdgcn_mfma_f32_16x16x32_bf16(aq[1], bp1, accR, 0, 0, 0);
                const int p = j * 16 + lm;
                const float bv = biascp[h * NT + min(plo_w + p, NT - 1)];
#pragma unroll
                for (int r = 0; r < 4; ++r) Rl[wave][quad * 4 + r][p] = accR[r] + bv;
            }
            asm volatile("" ::: "memory");   // order Rl write -> gather (same wave)

            // ---- e = exp((QK + R[t][t-s-plo_w]) / 9) * mask
#pragma unroll
            for (int j = 0; j < 4; ++j) {
                const int s_g = s0 + j * 16 + lm;
#pragma unroll
                for (int r = 0; r < 4; ++r) {
                    const int t_g = tw0 + quad * 4 + r;
                    float e = 0.f;
                    if (s_g <= t_g) {
                        const int p = t_g - s_g - plo_w;
                        e = __expf(fminf((accQK[j][r] + Rl[wave][quad * 4 + r][p]) * (1.f / 9.f), 60.f));
                    }
                    esl[wave][quad * 4 + r][j * 16 + lm] = f2b(e);
                    esum[r] += e;
                }
            }
            asm volatile("" ::: "memory");   // order esl write -> A-frag read (same wave)

            // ---- P.V: ctx[t][d] += e[t][s] * V[s][d]
            short8_t ae0 = *(const short8_t*)&esl[wave][lm][koff];
            short8_t ae1 = *(const short8_t*)&esl[wave][lm][koff + 32];
#pragma unroll
            for (int j = 0; j < 4; ++j) {
                short8_t bv0 = *(const short8_t*)&Vt[j * 16 + lm][koff];
                short8_t bv1 = *(const short8_t*)&Vt[j * 16 + lm][koff + 32];
                ctxacc[j] = __builtin_amdgcn_mfma_f32_16x16x32_bf16(ae0, bv0, ctxacc[j], 0, 0, 0);
                ctxacc[j] = __builtin_amdgcn_mfma_f32_16x16x32_bf16(ae1, bv1, ctxacc[j], 0, 0, 0);
            }
        }
    }

    // row-sum reduce within each quad's 16 lanes
    float rcpv[4];
#pragma unroll
    for (int r = 0; r < 4; ++r) {
        float v = esum[r];
        v += __shfl_xor(v, 1); v += __shfl_xor(v, 2);
        v += __shfl_xor(v, 4); v += __shfl_xor(v, 8);
        rcpv[r] = 1.f / (v + 2.f);
    }

    // write ctxT: channel = d*H + h, row t
#pragma unroll
    for (int j = 0; j < 4; ++j) {
        const int d = j * 16 + lm;
#pragma unroll
        for (int r = 0; r < 4; ++r) {
            const int t = tw0 + quad * 4 + r;
            ctxT[((size_t)(b * NT + t)) * ND + d * NH + h] = f2b(ctxacc[j][r] * rcpv[r]);
        }
    }
}

extern "C" void kernel_launch(void* const* d_in, const int* in_sizes, int n_in,
                              void* d_out, int out_size, void* d_ws, size_t ws_size,
                              hipStream_t stream)
{
    const float* x    = (const float*)d_in[0];
    const float* rpe  = (const float*)d_in[1];
    const float* rcb  = (const float*)d_in[2];
    const float* rpb  = (const float*)d_in[3];
    const float* Wqkv = (const float*)d_in[4];
    const float* bqkv = (const float*)d_in[5];
    const float* Wh   = (const float*)d_in[6];
    const float* bh   = (const float*)d_in[7];
    const float* Wp   = (const float*)d_in[8];
    const float* bp   = (const float*)d_in[9];

    float* out  = (float*)d_out;             // (B,T,D) fp32
    float* kout = out + 3145728;             // (B,H,DH,T) fp32
    float* vout = out + 6291456;             // (B,H,T,DH) fp32

    unsigned short* q_ws  = (unsigned short*)d_ws;   // (B,H,T,DH) bf16
    unsigned short* k_ws  = q_ws + 3145728;          // (B,H,T,DH) bf16
    unsigned short* v_ws  = k_ws + 3145728;          // (B,H,DH,T) bf16
    unsigned short* ctxT  = v_ws + 3145728;          // (B,T,D) bf16
    unsigned short* projb = ctxT + 3145728;          // (H,P,DH) bf16
    float* biascp = (float*)(projb + 393216);        // (H,P) f32 — ws ~24.8 MB

    gemm_mfma<0><<<dim3(2304 / 64, 4096 / 64), 256, 0, stream>>>(
        x, nullptr, Wqkv, bqkv, q_ws, kout, vout, k_ws, v_ws, 2304, 768, 2304);
    gemm_mfma<1><<<dim3(768 / 64, 512 / 64), 256, 0, stream>>>(
        rpe, nullptr, Wp, bp, projb, nullptr, nullptr, nullptr, nullptr, 768, 768, 768);
    biascp_kernel<<<dim3(12), 256, 0, stream>>>(rcb, rpb, projb, biascp);
    attn_mfma<<<dim3(NT / 64, 8 * NH), 256, 0, stream>>>(
        q_ws, k_ws, v_ws, projb, biascp, ctxT);
    gemm_mfma<2><<<dim3(768 / 64, 4096 / 64), 256, 0, stream>>>(
        nullptr, ctxT, Wh, bh, nullptr, out, nullptr, nullptr, nullptr, 768, 768, 768);
}

// Round 2
// 259.852 us; speedup vs baseline: 1.5724x; 1.1777x over previous
//
#include <hip/hip_runtime.h>
#include <hip/hip_bf16.h>

// SelfMaskedAttention (Transformer-XL rel-pos), B=8 T=512 D=768 H=12 DH=64.
// R12: QKV + output GEMMs rebuilt on the m97 structure: pre-pass converts
// x -> bf16 and Wqkv/Wh -> bf16 [N][K] (transposed), then a 128x128-tile GEMM
// (4 waves x 64x64 quadrant, acc[4][4], BK=32) stages both operands with
// global_load_lds width=16 into linear LDS -- no in-kernel f2b, no scatter.
// Attention (R11 structure) unchanged. xb aliases ctxT (disjoint live ranges).

#define NT 512
#define ND 768
#define NH 12

typedef short short4_t __attribute__((ext_vector_type(4)));
typedef short short8_t __attribute__((ext_vector_type(8)));
typedef float float4_t __attribute__((ext_vector_type(4)));

__device__ __forceinline__ float b2f(unsigned short u) {
    union { unsigned int i; float f; } x; x.i = ((unsigned int)u) << 16; return x.f;
}
__device__ __forceinline__ unsigned short f2b(float f) {
    union { float f; unsigned int i; } x; x.f = f;
    unsigned int i = x.i;
    i += 0x7fffu + ((i >> 16) & 1u);   // RNE
    return (unsigned short)(i >> 16);
}

// ---------------- pre-pass: fp32 -> bf16 elementwise ----------------
__global__ __launch_bounds__(256) void cvt_b(const float* __restrict__ in,
                                             unsigned short* __restrict__ out, int n8)
{
    const int i = blockIdx.x * 256 + threadIdx.x;
    if (i >= n8) return;
    const float* s = in + (size_t)i * 8;
    float4_t f0 = *(const float4_t*)s;
    float4_t f1 = *(const float4_t*)(s + 4);
    union { short8_t v; unsigned short u[8]; } pk;
    pk.u[0] = f2b(f0[0]); pk.u[1] = f2b(f0[1]); pk.u[2] = f2b(f0[2]); pk.u[3] = f2b(f0[3]);
    pk.u[4] = f2b(f1[0]); pk.u[5] = f2b(f1[1]); pk.u[6] = f2b(f1[2]); pk.u[7] = f2b(f1[3]);
    *(short8_t*)&out[(size_t)i * 8] = pk.v;
}

// ---------------- pre-pass: W [K][N] fp32 -> WT [N][K] bf16 (32x32 tiles) ----
__global__ __launch_bounds__(256) void transp_b(const float* __restrict__ in,
                                                unsigned short* __restrict__ out,
                                                int K, int N)
{
    __shared__ float t[32][33];
    const int k0 = blockIdx.y * 32;
    const int n0 = blockIdx.x * 32;
    const int r  = threadIdx.x >> 3;
    const int c  = (threadIdx.x & 7) * 4;
    float4_t v = *(const float4_t*)&in[(size_t)(k0 + r) * N + n0 + c];
    t[r][c + 0] = v[0]; t[r][c + 1] = v[1]; t[r][c + 2] = v[2]; t[r][c + 3] = v[3];
    __syncthreads();
    union { short4_t v; unsigned short u[4]; } pk;
    pk.u[0] = f2b(t[c + 0][r]);
    pk.u[1] = f2b(t[c + 1][r]);
    pk.u[2] = f2b(t[c + 2][r]);
    pk.u[3] = f2b(t[c + 3][r]);
    *(short4_t*)&out[(size_t)(n0 + r) * K + k0 + c] = pk.v;
}

// ---------------- 128x128-tile MFMA GEMM (m97 structure) ----------------
// A [M][K] bf16 row-major, BT [N][K] bf16 row-major. 256 thr = 4 waves,
// wave quadrant 64x64 (acc[4][4] of 16x16 frags). BK=32, staging via
// global_load_lds width=16 into linear LDS, 2 barriers per K-step.
template <int MODE>   // 0: QKV scatter epilogue, 2: plain fp32 [M][N]
__global__ __launch_bounds__(256) void gemm128(
    const unsigned short* __restrict__ A, const unsigned short* __restrict__ BT,
    const float* __restrict__ biasf,
    unsigned short* __restrict__ ob0, float* __restrict__ o1, float* __restrict__ o2,
    unsigned short* __restrict__ sh1, unsigned short* __restrict__ sh2,
    int K)
{
    __shared__ __attribute__((aligned(16))) unsigned short Al[128 * 32];
    __shared__ __attribute__((aligned(16))) unsigned short Bl[128 * 32];

    const int tid  = threadIdx.x;
    const int m0   = blockIdx.y * 128;
    const int n0   = blockIdx.x * 128;
    const int wave = tid >> 6;
    const int lane = tid & 63;
    const int lm   = lane & 15;
    const int quad = lane >> 4;
    const int wr   = (wave >> 1) * 64;   // wave row offset in tile
    const int wc   = (wave & 1) * 64;    // wave col offset in tile

    float4_t acc[4][4];
#pragma unroll
    for (int mt = 0; mt < 4; ++mt)
#pragma unroll
        for (int nt = 0; nt < 4; ++nt)
#pragma unroll
            for (int r = 0; r < 4; ++r) acc[mt][nt][r] = 0.f;

    // staging: issue i covers tile rows i*64 + tid/4, elem cols (tid&3)*8.
    // LDS linear: elem offset = tid*8 within issue half -> wave base + lane*16B.
    const unsigned short* ap = A  + (size_t)(m0 + (tid >> 2)) * K + (tid & 3) * 8;
    const unsigned short* bp = BT + (size_t)(n0 + (tid >> 2)) * K + (tid & 3) * 8;
    const size_t rstep = (size_t)64 * K;
    unsigned short* al0 = Al + wave * 512;
    unsigned short* bl0 = Bl + wave * 512;

    for (int k0 = 0; k0 < K; k0 += 32) {
        if (k0) __syncthreads();
        __builtin_amdgcn_global_load_lds(
            (const __attribute__((address_space(1))) void*)(ap + k0),
            (__attribute__((address_space(3))) void*)al0, 16, 0, 0);
        __builtin_amdgcn_global_load_lds(
            (const __attribute__((address_space(1))) void*)(ap + rstep + k0),
            (__attribute__((address_space(3))) void*)(al0 + 2048), 16, 0, 0);
        __builtin_amdgcn_global_load_lds(
            (const __attribute__((address_space(1))) void*)(bp + k0),
            (__attribute__((address_space(3))) void*)bl0, 16, 0, 0);
        __builtin_amdgcn_global_load_lds(
            (const __attribute__((address_space(1))) void*)(bp + rstep + k0),
            (__attribute__((address_space(3))) void*)(bl0 + 2048), 16, 0, 0);
        __syncthreads();   // drains vmcnt (compiler) -> tiles ready

        short8_t af[4], bf[4];
#pragma unroll
        for (int mt = 0; mt < 4; ++mt)
            af[mt] = *(const short8_t*)&Al[(wr + mt * 16 + lm) * 32 + quad * 8];
#pragma unroll
        for (int nt = 0; nt < 4; ++nt)
            bf[nt] = *(const short8_t*)&Bl[(wc + nt * 16 + lm) * 32 + quad * 8];
#pragma unroll
        for (int mt = 0; mt < 4; ++mt)
#pragma unroll
            for (int nt = 0; nt < 4; ++nt)
                acc[mt][nt] = __builtin_amdgcn_mfma_f32_16x16x32_bf16(af[mt], bf[nt], acc[mt][nt], 0, 0, 0);
    }

#pragma unroll
    for (int nt = 0; nt < 4; ++nt) {
        const int gcol = n0 + wc + nt * 16 + lm;
        const float bv = biasf[gcol];
#pragma unroll
        for (int mt = 0; mt < 4; ++mt) {
#pragma unroll
            for (int r = 0; r < 4; ++r) {
                const int grow = m0 + wr + mt * 16 + quad * 4 + r;
                const float val = acc[mt][nt][r] + bv;
                if (MODE == 0) {
                    int b = grow >> 9, t = grow & 511;
                    int sec = gcol / 768;
                    int cc = gcol - sec * 768;
                    int h = cc >> 6, d = cc & 63;
                    if (sec == 0) {
                        ob0[((size_t)((b * NH + h) * NT + t)) * 64 + d] = f2b(val);
                    } else if (sec == 1) {
                        o1[((size_t)((b * NH + h) * 64 + d)) * NT + t] = val;
                        sh1[((size_t)((b * NH + h) * NT + t)) * 64 + d] = f2b(val);
                    } else {
                        o2[((size_t)((b * NH + h) * NT + t)) * 64 + d] = val;
                        sh2[((size_t)((b * NH + h) * 64 + d)) * NT + t] = f2b(val);
                    }
                } else {
                    o1[(size_t)grow * ND + gcol] = val;
                }
            }
        }
    }
}

// ---------------- legacy 64x64 GEMM (kept for MODE 1: proj) ----------------
template <int MODE>
__global__ __launch_bounds__(256) void gemm_mfma(
    const float* __restrict__ Af, const unsigned short* __restrict__ Ab,
    const float* __restrict__ Bw, const float* __restrict__ biasf,
    unsigned short* __restrict__ ob0, float* __restrict__ o1, float* __restrict__ o2,
    int N, int K, int ldb)
{
    __shared__ unsigned short Al[64][40];
    __shared__ unsigned short Bl[64][40];

    const int tid  = threadIdx.x;
    const int m0   = blockIdx.y * 64;
    const int n0   = blockIdx.x * 64;
    const int wave = tid >> 6;
    const int lane = tid & 63;
    const int lm   = lane & 15;
    const int quad = lane >> 4;
    const int koff = quad * 8;

    float4_t acc[4];
#pragma unroll
    for (int j = 0; j < 4; ++j)
#pragma unroll
        for (int r = 0; r < 4; ++r) acc[j][r] = 0.0f;

    const int arow = tid >> 2;
    const int acg  = (tid & 3) * 8;
    const int bk   = tid & 31;
    const int bg   = tid >> 5;

    for (int k0 = 0; k0 < K; k0 += 32) {
        {
            const float* src = &Af[(size_t)(m0 + arow) * K + k0 + acg];
            float4_t f0 = *(const float4_t*)src;
            float4_t f1 = *(const float4_t*)(src + 4);
            union { short8_t v; unsigned short u[8]; } pk;
            pk.u[0] = f2b(f0[0]); pk.u[1] = f2b(f0[1]); pk.u[2] = f2b(f0[2]); pk.u[3] = f2b(f0[3]);
            pk.u[4] = f2b(f1[0]); pk.u[5] = f2b(f1[1]); pk.u[6] = f2b(f1[2]); pk.u[7] = f2b(f1[3]);
            *(short8_t*)&Al[arow][acg] = pk.v;
        }
        {
            const float* src = &Bw[(size_t)(k0 + bk) * ldb + n0 + bg * 8];
            float4_t f0 = *(const float4_t*)src;
            float4_t f1 = *(const float4_t*)(src + 4);
            Bl[bg * 8 + 0][bk] = f2b(f0[0]); Bl[bg * 8 + 1][bk] = f2b(f0[1]);
            Bl[bg * 8 + 2][bk] = f2b(f0[2]); Bl[bg * 8 + 3][bk] = f2b(f0[3]);
            Bl[bg * 8 + 4][bk] = f2b(f1[0]); Bl[bg * 8 + 5][bk] = f2b(f1[1]);
            Bl[bg * 8 + 6][bk] = f2b(f1[2]); Bl[bg * 8 + 7][bk] = f2b(f1[3]);
        }
        __syncthreads();

        short8_t af = *(const short8_t*)&Al[wave * 16 + lm][koff];
#pragma unroll
        for (int j = 0; j < 4; ++j) {
            short8_t bf = *(const short8_t*)&Bl[j * 16 + lm][koff];
            acc[j] = __builtin_amdgcn_mfma_f32_16x16x32_bf16(af, bf, acc[j], 0, 0, 0);
        }
        __syncthreads();
    }

#pragma unroll
    for (int j = 0; j < 4; ++j) {
        const int gcol = n0 + j * 16 + lm;
        const float bv = biasf[gcol];
#pragma unroll
        for (int r = 0; r < 4; ++r) {
            const int grow = m0 + wave * 16 + quad * 4 + r;
            const float val = acc[j][r] + bv;
            if (MODE == 1) {
                int h = gcol >> 6, d = gcol & 63;
                ob0[((size_t)(h * NT + grow)) * 64 + d] = f2b(val);   // projb bf16
            }
        }
    }
}

// ---------------- bias_cp (reads bf16 projb) ----------------
__global__ __launch_bounds__(256) void biascp_kernel(
    const float* __restrict__ rcb, const float* __restrict__ rpb,
    const unsigned short* __restrict__ projb, float* __restrict__ biascp)
{
    __shared__ float cb[64];
    const int h = blockIdx.x;
    const int tid = threadIdx.x;
    if (tid < 64) cb[tid] = rcb[h * 64 + tid] + rpb[h * 64 + tid];
    __syncthreads();
    for (int p = tid; p < NT; p += 256) {
        const unsigned short* pr = &projb[((size_t)(h * NT + p)) * 64];
        float s = 0.f;
#pragma unroll 8
        for (int d = 0; d < 64; ++d) s += b2f(pr[d]) * cb[d];
        biascp[h * NT + p] = s;
    }
}

// ---------------- MFMA attention (R11, unchanged) ----------------
__global__ __launch_bounds__(256) void attn_mfma(
    const unsigned short* __restrict__ q_ws, const unsigned short* __restrict__ k_ws,
    const unsigned short* __restrict__ v_ws, const unsigned short* __restrict__ projb,
    const float* __restrict__ biascp, unsigned short* __restrict__ ctxT)
{
    __shared__ unsigned short Kt[64][72];    // [s][d] bf16
    __shared__ unsigned short Vt[64][72];    // [d][s] bf16
    __shared__ unsigned short pP[128][72];   // [p][d] bf16 (block rel-window)
    __shared__ float          Rl[4][16][84]; // per-wave R + bias, f32
    __shared__ unsigned short esl[4][16][72];// per-wave e bf16 (PV A-operand)

    const int tid  = threadIdx.x;
    const int y    = blockIdx.y;        // b*H + h
    const int h    = y % NH;
    const int b    = y / NH;
    const int t0   = blockIdx.x * 64;
    const int wave = tid >> 6;
    const int lane = tid & 63;
    const int lm   = lane & 15;
    const int quad = lane >> 4;
    const int koff = quad * 8;
    const int tw0  = t0 + wave * 16;
    const int nst  = (t0 >> 6) + 1;

    short8_t aq[2];
    aq[0] = *(const short8_t*)&q_ws[((size_t)(y * NT + tw0 + lm)) * 64 + koff];
    aq[1] = *(const short8_t*)&q_ws[((size_t)(y * NT + tw0 + lm)) * 64 + koff + 32];

    float4_t ctxacc[4];
#pragma unroll
    for (int j = 0; j < 4; ++j)
#pragma unroll
        for (int r = 0; r < 4; ++r) ctxacc[j][r] = 0.f;
    float esum[4] = {0.f, 0.f, 0.f, 0.f};

    const int sr = tid >> 2;           // staging row 0..63
    const int sc = (tid & 3) * 16;     // 16-short chunk
    const int pr = tid >> 1;           // proj row 0..127
    const int pc = (tid & 1) * 32;     // 32-short chunk

    for (int st = 0; st < nst; ++st) {
        const int s0      = st * 64;
        const int plo_blk = max(0, t0 - s0 - 63);
        const int cnt_blk = t0 + 63 - s0 - plo_blk + 1;   // 64..127
        if (st) __syncthreads();
        {   // ---- stage K^T [s][d], V^T [d][s], proj window — all short8 copies
            const unsigned short* ks = &k_ws[((size_t)(y * NT + s0 + sr)) * 64 + sc];
            *(short8_t*)&Kt[sr][sc]     = *(const short8_t*)ks;
            *(short8_t*)&Kt[sr][sc + 8] = *(const short8_t*)(ks + 8);
            const unsigned short* vs = &v_ws[((size_t)(y * 64 + sr)) * NT + s0 + sc];
            *(short8_t*)&Vt[sr][sc]     = *(const short8_t*)vs;
            *(short8_t*)&Vt[sr][sc + 8] = *(const short8_t*)(vs + 8);
            if (pr < cnt_blk) {
                const unsigned short* ps = &projb[((size_t)(h * NT + plo_blk + pr)) * 64 + pc];
                *(short8_t*)&pP[pr][pc]      = *(const short8_t*)ps;
                *(short8_t*)&pP[pr][pc + 8]  = *(const short8_t*)(ps + 8);
                *(short8_t*)&pP[pr][pc + 16] = *(const short8_t*)(ps + 16);
                *(short8_t*)&pP[pr][pc + 24] = *(const short8_t*)(ps + 24);
            }
        }
        __syncthreads();

        if (s0 <= tw0 + 15) {
            const int plo_w = max(0, tw0 - s0 - 63);
            const int pbase = plo_w - plo_blk;            // multiple of 16
            const int cntw  = tw0 + 15 - s0 - plo_w + 1;  // 16..79
            const int jmax  = min(3, (tw0 + 15 - s0) >> 4);
            const int jpmax = (cntw - 1) >> 4;            // <= 4

            float4_t accQK[4];
#pragma unroll
            for (int j = 0; j < 4; ++j)
#pragma unroll
                for (int r = 0; r < 4; ++r) accQK[j][r] = 0.f;
            for (int j = 0; j <= jmax; ++j) {
                short8_t bk0 = *(const short8_t*)&Kt[j * 16 + lm][koff];
                short8_t bk1 = *(const short8_t*)&Kt[j * 16 + lm][koff + 32];
                accQK[j] = __builtin_amdgcn_mfma_f32_16x16x32_bf16(aq[0], bk0, accQK[j], 0, 0, 0);
                accQK[j] = __builtin_amdgcn_mfma_f32_16x16x32_bf16(aq[1], bk1, accQK[j], 0, 0, 0);
            }
            for (int j = 0; j <= jpmax; ++j) {
                short8_t bp0 = *(const short8_t*)&pP[pbase + j * 16 + lm][koff];
                short8_t bp1 = *(const short8_t*)&pP[pbase + j * 16 + lm][koff + 32];
                float4_t accR;
#pragma unroll
                for (int r = 0; r < 4; ++r) accR[r] = 0.f;
                accR = __builtin_amdgcn_mfma_f32_16x16x32_bf16(aq[0], bp0, accR, 0, 0, 0);
                accR = __builtin_amdgcn_mfma_f32_16x16x32_bf16(aq[1], bp1, accR, 0, 0, 0);
                const int p = j * 16 + lm;
                const float bv = biascp[h * NT + min(plo_w + p, NT - 1)];
#pragma unroll
                for (int r = 0; r < 4; ++r) Rl[wave][quad * 4 + r][p] = accR[r] + bv;
            }
            asm volatile("" ::: "memory");

#pragma unroll
            for (int j = 0; j < 4; ++j) {
                const int s_g = s0 + j * 16 + lm;
#pragma unroll
                for (int r = 0; r < 4; ++r) {
                    const int t_g = tw0 + quad * 4 + r;
                    float e = 0.f;
                    if (s_g <= t_g) {
                        const int p = t_g - s_g - plo_w;
                        e = __expf(fminf((accQK[j][r] + Rl[wave][quad * 4 + r][p]) * (1.f / 9.f), 60.f));
                    }
                    esl[wave][quad * 4 + r][j * 16 + lm] = f2b(e);
                    esum[r] += e;
                }
            }
            asm volatile("" ::: "memory");

            short8_t ae0 = *(const short8_t*)&esl[wave][lm][koff];
            short8_t ae1 = *(const short8_t*)&esl[wave][lm][koff + 32];
#pragma unroll
            for (int j = 0; j < 4; ++j) {
                short8_t bv0 = *(const short8_t*)&Vt[j * 16 + lm][koff];
                short8_t bv1 = *(const short8_t*)&Vt[j * 16 + lm][koff + 32];
                ctxacc[j] = __builtin_amdgcn_mfma_f32_16x16x32_bf16(ae0, bv0, ctxacc[j], 0, 0, 0);
                ctxacc[j] = __builtin_amdgcn_mfma_f32_16x16x32_bf16(ae1, bv1, ctxacc[j], 0, 0, 0);
            }
        }
    }

    float rcpv[4];
#pragma unroll
    for (int r = 0; r < 4; ++r) {
        float v = esum[r];
        v += __shfl_xor(v, 1); v += __shfl_xor(v, 2);
        v += __shfl_xor(v, 4); v += __shfl_xor(v, 8);
        rcpv[r] = 1.f / (v + 2.f);
    }

#pragma unroll
    for (int j = 0; j < 4; ++j) {
        const int d = j * 16 + lm;
#pragma unroll
        for (int r = 0; r < 4; ++r) {
            const int t = tw0 + quad * 4 + r;
            ctxT[((size_t)(b * NT + t)) * ND + d * NH + h] = f2b(ctxacc[j][r] * rcpv[r]);
        }
    }
}

extern "C" void kernel_launch(void* const* d_in, const int* in_sizes, int n_in,
                              void* d_out, int out_size, void* d_ws, size_t ws_size,
                              hipStream_t stream)
{
    const float* x    = (const float*)d_in[0];
    const float* rpe  = (const float*)d_in[1];
    const float* rcb  = (const float*)d_in[2];
    const float* rpb  = (const float*)d_in[3];
    const float* Wqkv = (const float*)d_in[4];
    const float* bqkv = (const float*)d_in[5];
    const float* Wh   = (const float*)d_in[6];
    const float* bh   = (const float*)d_in[7];
    const float* Wp   = (const float*)d_in[8];
    const float* bp   = (const float*)d_in[9];

    float* out  = (float*)d_out;             // (B,T,D) fp32
    float* kout = out + 3145728;             // (B,H,DH,T) fp32
    float* vout = out + 6291456;             // (B,H,T,DH) fp32

    unsigned short* q_ws  = (unsigned short*)d_ws;   // (B,H,T,DH) bf16
    unsigned short* k_ws  = q_ws + 3145728;          // (B,H,T,DH) bf16
    unsigned short* v_ws  = k_ws + 3145728;          // (B,H,DH,T) bf16
    unsigned short* ctxT  = v_ws + 3145728;          // (B,T,D) bf16  [= xb alias]
    unsigned short* xb    = ctxT;                    // x bf16 [4096][768] (pre-attn)
    unsigned short* projb = ctxT + 3145728;          // (H,P,DH) bf16
    float* biascp = (float*)(projb + 393216);        // (H,P) f32
    unsigned short* WqkvT = (unsigned short*)(biascp + 6144);  // [2304][768] bf16
    unsigned short* WhT   = WqkvT + 1769472;         // [768][768] bf16 — ws ~30.7 MB

    // pre-pass: bf16 operands in MFMA-ready layouts
    cvt_b<<<dim3(1536), 256, 0, stream>>>(x, xb, 393216);
    transp_b<<<dim3(2304 / 32, 768 / 32), 256, 0, stream>>>(Wqkv, WqkvT, 768, 2304);
    transp_b<<<dim3(768 / 32, 768 / 32), 256, 0, stream>>>(Wh, WhT, 768, 768);

    gemm128<0><<<dim3(2304 / 128, 4096 / 128), 256, 0, stream>>>(
        xb, WqkvT, bqkv, q_ws, kout, vout, k_ws, v_ws, 768);
    gemm_mfma<1><<<dim3(768 / 64, 512 / 64), 256, 0, stream>>>(
        rpe, nullptr, Wp, bp, projb, nullptr, nullptr, 768, 768, 768);
    biascp_kernel<<<dim3(12), 256, 0, stream>>>(rcb, rpb, projb, biascp);
    attn_mfma<<<dim3(NT / 64, 8 * NH), 256, 0, stream>>>(
        q_ws, k_ws, v_ws, projb, biascp, ctxT);
    gemm128<2><<<dim3(768 / 128, 4096 / 128), 256, 0, stream>>>(
        ctxT, WhT, bh, nullptr, out, nullptr, nullptr, nullptr, 768);
}

// Round 3
// 241.518 us; speedup vs baseline: 1.6917x; 1.0759x over previous
//
#include <hip/hip_runtime.h>
#include <hip/hip_bf16.h>

// SelfMaskedAttention (Transformer-XL rel-pos), B=8 T=512 D=768 H=12 DH=64.
// R13: attention load-balance. 32-row t-tiles, block = pair (i, 15-i) processed
// sequentially -> every block costs exactly 9 s-tile units (causal triangle
// balanced by construction). 768 blocks x 128 thr, ~47.6 KB LDS -> 3 blocks/CU,
// entire grid resident. GEMMs (m97-structure 128x128) unchanged from R12.

#define NT 512
#define ND 768
#define NH 12

typedef short short4_t __attribute__((ext_vector_type(4)));
typedef short short8_t __attribute__((ext_vector_type(8)));
typedef float float4_t __attribute__((ext_vector_type(4)));

__device__ __forceinline__ float b2f(unsigned short u) {
    union { unsigned int i; float f; } x; x.i = ((unsigned int)u) << 16; return x.f;
}
__device__ __forceinline__ unsigned short f2b(float f) {
    union { float f; unsigned int i; } x; x.f = f;
    unsigned int i = x.i;
    i += 0x7fffu + ((i >> 16) & 1u);   // RNE
    return (unsigned short)(i >> 16);
}

// ---------------- pre-pass: fp32 -> bf16 elementwise ----------------
__global__ __launch_bounds__(256) void cvt_b(const float* __restrict__ in,
                                             unsigned short* __restrict__ out, int n8)
{
    const int i = blockIdx.x * 256 + threadIdx.x;
    if (i >= n8) return;
    const float* s = in + (size_t)i * 8;
    float4_t f0 = *(const float4_t*)s;
    float4_t f1 = *(const float4_t*)(s + 4);
    union { short8_t v; unsigned short u[8]; } pk;
    pk.u[0] = f2b(f0[0]); pk.u[1] = f2b(f0[1]); pk.u[2] = f2b(f0[2]); pk.u[3] = f2b(f0[3]);
    pk.u[4] = f2b(f1[0]); pk.u[5] = f2b(f1[1]); pk.u[6] = f2b(f1[2]); pk.u[7] = f2b(f1[3]);
    *(short8_t*)&out[(size_t)i * 8] = pk.v;
}

// ---------------- pre-pass: W [K][N] fp32 -> WT [N][K] bf16 (32x32 tiles) ----
__global__ __launch_bounds__(256) void transp_b(const float* __restrict__ in,
                                                unsigned short* __restrict__ out,
                                                int K, int N)
{
    __shared__ float t[32][33];
    const int k0 = blockIdx.y * 32;
    const int n0 = blockIdx.x * 32;
    const int r  = threadIdx.x >> 3;
    const int c  = (threadIdx.x & 7) * 4;
    float4_t v = *(const float4_t*)&in[(size_t)(k0 + r) * N + n0 + c];
    t[r][c + 0] = v[0]; t[r][c + 1] = v[1]; t[r][c + 2] = v[2]; t[r][c + 3] = v[3];
    __syncthreads();
    union { short4_t v; unsigned short u[4]; } pk;
    pk.u[0] = f2b(t[c + 0][r]);
    pk.u[1] = f2b(t[c + 1][r]);
    pk.u[2] = f2b(t[c + 2][r]);
    pk.u[3] = f2b(t[c + 3][r]);
    *(short4_t*)&out[(size_t)(n0 + r) * K + k0 + c] = pk.v;
}

// ---------------- 128x128-tile MFMA GEMM (m97 structure) ----------------
template <int MODE>   // 0: QKV scatter epilogue, 2: plain fp32 [M][N]
__global__ __launch_bounds__(256) void gemm128(
    const unsigned short* __restrict__ A, const unsigned short* __restrict__ BT,
    const float* __restrict__ biasf,
    unsigned short* __restrict__ ob0, float* __restrict__ o1, float* __restrict__ o2,
    unsigned short* __restrict__ sh1, unsigned short* __restrict__ sh2,
    int K)
{
    __shared__ __attribute__((aligned(16))) unsigned short Al[128 * 32];
    __shared__ __attribute__((aligned(16))) unsigned short Bl[128 * 32];

    const int tid  = threadIdx.x;
    const int m0   = blockIdx.y * 128;
    const int n0   = blockIdx.x * 128;
    const int wave = tid >> 6;
    const int lane = tid & 63;
    const int lm   = lane & 15;
    const int quad = lane >> 4;
    const int wr   = (wave >> 1) * 64;
    const int wc   = (wave & 1) * 64;

    float4_t acc[4][4];
#pragma unroll
    for (int mt = 0; mt < 4; ++mt)
#pragma unroll
        for (int nt = 0; nt < 4; ++nt)
#pragma unroll
            for (int r = 0; r < 4; ++r) acc[mt][nt][r] = 0.f;

    const unsigned short* ap = A  + (size_t)(m0 + (tid >> 2)) * K + (tid & 3) * 8;
    const unsigned short* bp = BT + (size_t)(n0 + (tid >> 2)) * K + (tid & 3) * 8;
    const size_t rstep = (size_t)64 * K;
    unsigned short* al0 = Al + wave * 512;
    unsigned short* bl0 = Bl + wave * 512;

    for (int k0 = 0; k0 < K; k0 += 32) {
        if (k0) __syncthreads();
        __builtin_amdgcn_global_load_lds(
            (const __attribute__((address_space(1))) void*)(ap + k0),
            (__attribute__((address_space(3))) void*)al0, 16, 0, 0);
        __builtin_amdgcn_global_load_lds(
            (const __attribute__((address_space(1))) void*)(ap + rstep + k0),
            (__attribute__((address_space(3))) void*)(al0 + 2048), 16, 0, 0);
        __builtin_amdgcn_global_load_lds(
            (const __attribute__((address_space(1))) void*)(bp + k0),
            (__attribute__((address_space(3))) void*)bl0, 16, 0, 0);
        __builtin_amdgcn_global_load_lds(
            (const __attribute__((address_space(1))) void*)(bp + rstep + k0),
            (__attribute__((address_space(3))) void*)(bl0 + 2048), 16, 0, 0);
        __syncthreads();

        short8_t af[4], bf[4];
#pragma unroll
        for (int mt = 0; mt < 4; ++mt)
            af[mt] = *(const short8_t*)&Al[(wr + mt * 16 + lm) * 32 + quad * 8];
#pragma unroll
        for (int nt = 0; nt < 4; ++nt)
            bf[nt] = *(const short8_t*)&Bl[(wc + nt * 16 + lm) * 32 + quad * 8];
#pragma unroll
        for (int mt = 0; mt < 4; ++mt)
#pragma unroll
            for (int nt = 0; nt < 4; ++nt)
                acc[mt][nt] = __builtin_amdgcn_mfma_f32_16x16x32_bf16(af[mt], bf[nt], acc[mt][nt], 0, 0, 0);
    }

#pragma unroll
    for (int nt = 0; nt < 4; ++nt) {
        const int gcol = n0 + wc + nt * 16 + lm;
        const float bv = biasf[gcol];
#pragma unroll
        for (int mt = 0; mt < 4; ++mt) {
#pragma unroll
            for (int r = 0; r < 4; ++r) {
                const int grow = m0 + wr + mt * 16 + quad * 4 + r;
                const float val = acc[mt][nt][r] + bv;
                if (MODE == 0) {
                    int b = grow >> 9, t = grow & 511;
                    int sec = gcol / 768;
                    int cc = gcol - sec * 768;
                    int h = cc >> 6, d = cc & 63;
                    if (sec == 0) {
                        ob0[((size_t)((b * NH + h) * NT + t)) * 64 + d] = f2b(val);
                    } else if (sec == 1) {
                        o1[((size_t)((b * NH + h) * 64 + d)) * NT + t] = val;
                        sh1[((size_t)((b * NH + h) * NT + t)) * 64 + d] = f2b(val);
                    } else {
                        o2[((size_t)((b * NH + h) * NT + t)) * 64 + d] = val;
                        sh2[((size_t)((b * NH + h) * 64 + d)) * NT + t] = f2b(val);
                    }
                } else {
                    o1[(size_t)grow * ND + gcol] = val;
                }
            }
        }
    }
}

// ---------------- legacy 64x64 GEMM (MODE 1: proj) ----------------
template <int MODE>
__global__ __launch_bounds__(256) void gemm_mfma(
    const float* __restrict__ Af, const unsigned short* __restrict__ Ab,
    const float* __restrict__ Bw, const float* __restrict__ biasf,
    unsigned short* __restrict__ ob0, float* __restrict__ o1, float* __restrict__ o2,
    int N, int K, int ldb)
{
    __shared__ unsigned short Al[64][40];
    __shared__ unsigned short Bl[64][40];

    const int tid  = threadIdx.x;
    const int m0   = blockIdx.y * 64;
    const int n0   = blockIdx.x * 64;
    const int wave = tid >> 6;
    const int lane = tid & 63;
    const int lm   = lane & 15;
    const int quad = lane >> 4;
    const int koff = quad * 8;

    float4_t acc[4];
#pragma unroll
    for (int j = 0; j < 4; ++j)
#pragma unroll
        for (int r = 0; r < 4; ++r) acc[j][r] = 0.0f;

    const int arow = tid >> 2;
    const int acg  = (tid & 3) * 8;
    const int bk   = tid & 31;
    const int bg   = tid >> 5;

    for (int k0 = 0; k0 < K; k0 += 32) {
        {
            const float* src = &Af[(size_t)(m0 + arow) * K + k0 + acg];
            float4_t f0 = *(const float4_t*)src;
            float4_t f1 = *(const float4_t*)(src + 4);
            union { short8_t v; unsigned short u[8]; } pk;
            pk.u[0] = f2b(f0[0]); pk.u[1] = f2b(f0[1]); pk.u[2] = f2b(f0[2]); pk.u[3] = f2b(f0[3]);
            pk.u[4] = f2b(f1[0]); pk.u[5] = f2b(f1[1]); pk.u[6] = f2b(f1[2]); pk.u[7] = f2b(f1[3]);
            *(short8_t*)&Al[arow][acg] = pk.v;
        }
        {
            const float* src = &Bw[(size_t)(k0 + bk) * ldb + n0 + bg * 8];
            float4_t f0 = *(const float4_t*)src;
            float4_t f1 = *(const float4_t*)(src + 4);
            Bl[bg * 8 + 0][bk] = f2b(f0[0]); Bl[bg * 8 + 1][bk] = f2b(f0[1]);
            Bl[bg * 8 + 2][bk] = f2b(f0[2]); Bl[bg * 8 + 3][bk] = f2b(f0[3]);
            Bl[bg * 8 + 4][bk] = f2b(f1[0]); Bl[bg * 8 + 5][bk] = f2b(f1[1]);
            Bl[bg * 8 + 6][bk] = f2b(f1[2]); Bl[bg * 8 + 7][bk] = f2b(f1[3]);
        }
        __syncthreads();

        short8_t af = *(const short8_t*)&Al[wave * 16 + lm][koff];
#pragma unroll
        for (int j = 0; j < 4; ++j) {
            short8_t bf = *(const short8_t*)&Bl[j * 16 + lm][koff];
            acc[j] = __builtin_amdgcn_mfma_f32_16x16x32_bf16(af, bf, acc[j], 0, 0, 0);
        }
        __syncthreads();
    }

#pragma unroll
    for (int j = 0; j < 4; ++j) {
        const int gcol = n0 + j * 16 + lm;
        const float bv = biasf[gcol];
#pragma unroll
        for (int r = 0; r < 4; ++r) {
            const int grow = m0 + wave * 16 + quad * 4 + r;
            const float val = acc[j][r] + bv;
            if (MODE == 1) {
                int h = gcol >> 6, d = gcol & 63;
                ob0[((size_t)(h * NT + grow)) * 64 + d] = f2b(val);   // projb bf16
            }
        }
    }
}

// ---------------- bias_cp (reads bf16 projb) ----------------
__global__ __launch_bounds__(256) void biascp_kernel(
    const float* __restrict__ rcb, const float* __restrict__ rpb,
    const unsigned short* __restrict__ projb, float* __restrict__ biascp)
{
    __shared__ float cb[64];
    const int h = blockIdx.x;
    const int tid = threadIdx.x;
    if (tid < 64) cb[tid] = rcb[h * 64 + tid] + rpb[h * 64 + tid];
    __syncthreads();
    for (int p = tid; p < NT; p += 256) {
        const unsigned short* pr = &projb[((size_t)(h * NT + p)) * 64];
        float s = 0.f;
#pragma unroll 8
        for (int d = 0; d < 64; ++d) s += b2f(pr[d]) * cb[d];
        biascp[h * NT + p] = s;
    }
}

// ---------------- MFMA attention: grid (8, 96), 128 thr, paired 32-row tiles --
// Block handles t-tiles i=15-pairi (long chain) then i=pairi; every block does
// exactly 9 s-tile units. 2 waves, wave w owns rows [tb0+16w, tb0+16w+15].
__global__ __launch_bounds__(128) void attn_mfma(
    const unsigned short* __restrict__ q_ws, const unsigned short* __restrict__ k_ws,
    const unsigned short* __restrict__ v_ws, const unsigned short* __restrict__ projb,
    const float* __restrict__ biascp, unsigned short* __restrict__ ctxT)
{
    __shared__ unsigned short Kt[64][72];    // [s][d] bf16
    __shared__ unsigned short Vt[64][72];    // [d][s] bf16
    __shared__ unsigned short pP[96][72];    // [p][d] bf16 (tile rel-window)
    __shared__ float          Rl[2][16][84]; // per-wave R + bias, f32
    __shared__ unsigned short esl[2][16][72];// per-wave e bf16 (PV A-operand)

    const int tid   = threadIdx.x;
    const int y     = blockIdx.y;       // b*H + h
    const int h     = y % NH;
    const int b     = y / NH;
    const int pairi = blockIdx.x;       // 0..7
    const int wave  = tid >> 6;
    const int lane  = tid & 63;
    const int lm    = lane & 15;
    const int quad  = lane >> 4;
    const int koff  = quad * 8;

    const int sr = tid >> 1;           // staging row 0..63
    const int sc = (tid & 1) * 32;     // 32-short chunk

    for (int c = 0; c < 2; ++c) {
        const int ti  = c ? pairi : (15 - pairi);
        const int tb0 = ti * 32;
        const int tw0 = tb0 + wave * 16;
        const int nst = (tb0 >> 6) + 1;

        short8_t aq[2];
        aq[0] = *(const short8_t*)&q_ws[((size_t)(y * NT + tw0 + lm)) * 64 + koff];
        aq[1] = *(const short8_t*)&q_ws[((size_t)(y * NT + tw0 + lm)) * 64 + koff + 32];

        float4_t ctxacc[4];
#pragma unroll
        for (int j = 0; j < 4; ++j)
#pragma unroll
            for (int r = 0; r < 4; ++r) ctxacc[j][r] = 0.f;
        float esum[4] = {0.f, 0.f, 0.f, 0.f};

        for (int st = 0; st < nst; ++st) {
            const int s0      = st * 64;
            const int plo_blk = max(0, tb0 - s0 - 63);
            const int cnt_blk = tb0 + 31 - s0 - plo_blk + 1;   // 32..95
            if (c | st) __syncthreads();
            {   // ---- stage K^T [s][d], V^T [d][s], proj window — short8 copies
                const unsigned short* ks = &k_ws[((size_t)(y * NT + s0 + sr)) * 64 + sc];
                *(short8_t*)&Kt[sr][sc]      = *(const short8_t*)ks;
                *(short8_t*)&Kt[sr][sc + 8]  = *(const short8_t*)(ks + 8);
                *(short8_t*)&Kt[sr][sc + 16] = *(const short8_t*)(ks + 16);
                *(short8_t*)&Kt[sr][sc + 24] = *(const short8_t*)(ks + 24);
                const unsigned short* vs = &v_ws[((size_t)(y * 64 + sr)) * NT + s0 + sc];
                *(short8_t*)&Vt[sr][sc]      = *(const short8_t*)vs;
                *(short8_t*)&Vt[sr][sc + 8]  = *(const short8_t*)(vs + 8);
                *(short8_t*)&Vt[sr][sc + 16] = *(const short8_t*)(vs + 16);
                *(short8_t*)&Vt[sr][sc + 24] = *(const short8_t*)(vs + 24);
                for (int p = tid; p < cnt_blk; p += 128) {
                    const unsigned short* ps = &projb[((size_t)(h * NT + plo_blk + p)) * 64];
                    *(short8_t*)&pP[p][0]  = *(const short8_t*)ps;
                    *(short8_t*)&pP[p][8]  = *(const short8_t*)(ps + 8);
                    *(short8_t*)&pP[p][16] = *(const short8_t*)(ps + 16);
                    *(short8_t*)&pP[p][24] = *(const short8_t*)(ps + 24);
                    *(short8_t*)&pP[p][32] = *(const short8_t*)(ps + 32);
                    *(short8_t*)&pP[p][40] = *(const short8_t*)(ps + 40);
                    *(short8_t*)&pP[p][48] = *(const short8_t*)(ps + 48);
                    *(short8_t*)&pP[p][56] = *(const short8_t*)(ps + 56);
                }
                // rows >= cnt_blk left stale: they feed only R columns p >= cntw,
                // which are never gathered (proof: cnt_blk - pbase >= cntw).
            }
            __syncthreads();

            if (s0 <= tw0 + 15) {   // wave-uniform: wave has active s here
                const int plo_w = max(0, tw0 - s0 - 63);
                const int pbase = plo_w - plo_blk;            // 0 or 16
                const int cntw  = tw0 + 15 - s0 - plo_w + 1;  // 16..79
                const int jmax  = min(3, (tw0 + 15 - s0) >> 4);
                const int jpmax = (cntw - 1) >> 4;            // <= 4

                // ---- QK^T
                float4_t accQK[4];
#pragma unroll
                for (int j = 0; j < 4; ++j)
#pragma unroll
                    for (int r = 0; r < 4; ++r) accQK[j][r] = 0.f;
                for (int j = 0; j <= jmax; ++j) {
                    short8_t bk0 = *(const short8_t*)&Kt[j * 16 + lm][koff];
                    short8_t bk1 = *(const short8_t*)&Kt[j * 16 + lm][koff + 32];
                    accQK[j] = __builtin_amdgcn_mfma_f32_16x16x32_bf16(aq[0], bk0, accQK[j], 0, 0, 0);
                    accQK[j] = __builtin_amdgcn_mfma_f32_16x16x32_bf16(aq[1], bk1, accQK[j], 0, 0, 0);
                }
                // ---- R = Q . proj^T, bias folded at write
                for (int j = 0; j <= jpmax; ++j) {
                    short8_t bp0 = *(const short8_t*)&pP[pbase + j * 16 + lm][koff];
                    short8_t bp1 = *(const short8_t*)&pP[pbase + j * 16 + lm][koff + 32];
                    float4_t accR;
#pragma unroll
                    for (int r = 0; r < 4; ++r) accR[r] = 0.f;
                    accR = __builtin_amdgcn_mfma_f32_16x16x32_bf16(aq[0], bp0, accR, 0, 0, 0);
                    accR = __builtin_amdgcn_mfma_f32_16x16x32_bf16(aq[1], bp1, accR, 0, 0, 0);
                    const int p = j * 16 + lm;
                    const float bv = biascp[h * NT + min(plo_w + p, NT - 1)];
#pragma unroll
                    for (int r = 0; r < 4; ++r) Rl[wave][quad * 4 + r][p] = accR[r] + bv;
                }
                asm volatile("" ::: "memory");   // order Rl write -> gather (same wave)

                // ---- e = exp((QK + R[t][t-s-plo_w]) / 9) * mask
#pragma unroll
                for (int j = 0; j < 4; ++j) {
                    const int s_g = s0 + j * 16 + lm;
#pragma unroll
                    for (int r = 0; r < 4; ++r) {
                        const int t_g = tw0 + quad * 4 + r;
                        float e = 0.f;
                        if (s_g <= t_g) {
                            const int p = t_g - s_g - plo_w;
                            e = __expf(fminf((accQK[j][r] + Rl[wave][quad * 4 + r][p]) * (1.f / 9.f), 60.f));
                        }
                        esl[wave][quad * 4 + r][j * 16 + lm] = f2b(e);
                        esum[r] += e;
                    }
                }
                asm volatile("" ::: "memory");   // order esl write -> A-frag read

                // ---- P.V: ctx[t][d] += e[t][s] * V[s][d]
                short8_t ae0 = *(const short8_t*)&esl[wave][lm][koff];
                short8_t ae1 = *(const short8_t*)&esl[wave][lm][koff + 32];
#pragma unroll
                for (int j = 0; j < 4; ++j) {
                    short8_t bv0 = *(const short8_t*)&Vt[j * 16 + lm][koff];
                    short8_t bv1 = *(const short8_t*)&Vt[j * 16 + lm][koff + 32];
                    ctxacc[j] = __builtin_amdgcn_mfma_f32_16x16x32_bf16(ae0, bv0, ctxacc[j], 0, 0, 0);
                    ctxacc[j] = __builtin_amdgcn_mfma_f32_16x16x32_bf16(ae1, bv1, ctxacc[j], 0, 0, 0);
                }
            }
        }

        // ---- per-tile epilogue: reduce esum within quad, normalize, store
        float rcpv[4];
#pragma unroll
        for (int r = 0; r < 4; ++r) {
            float v = esum[r];
            v += __shfl_xor(v, 1); v += __shfl_xor(v, 2);
            v += __shfl_xor(v, 4); v += __shfl_xor(v, 8);
            rcpv[r] = 1.f / (v + 2.f);
        }
#pragma unroll
        for (int j = 0; j < 4; ++j) {
            const int d = j * 16 + lm;
#pragma unroll
            for (int r = 0; r < 4; ++r) {
                const int t = tw0 + quad * 4 + r;
                ctxT[((size_t)(b * NT + t)) * ND + d * NH + h] = f2b(ctxacc[j][r] * rcpv[r]);
            }
        }
    }
}

extern "C" void kernel_launch(void* const* d_in, const int* in_sizes, int n_in,
                              void* d_out, int out_size, void* d_ws, size_t ws_size,
                              hipStream_t stream)
{
    const float* x    = (const float*)d_in[0];
    const float* rpe  = (const float*)d_in[1];
    const float* rcb  = (const float*)d_in[2];
    const float* rpb  = (const float*)d_in[3];
    const float* Wqkv = (const float*)d_in[4];
    const float* bqkv = (const float*)d_in[5];
    const float* Wh   = (const float*)d_in[6];
    const float* bh   = (const float*)d_in[7];
    const float* Wp   = (const float*)d_in[8];
    const float* bp   = (const float*)d_in[9];

    float* out  = (float*)d_out;             // (B,T,D) fp32
    float* kout = out + 3145728;             // (B,H,DH,T) fp32
    float* vout = out + 6291456;             // (B,H,T,DH) fp32

    unsigned short* q_ws  = (unsigned short*)d_ws;   // (B,H,T,DH) bf16
    unsigned short* k_ws  = q_ws + 3145728;          // (B,H,T,DH) bf16
    unsigned short* v_ws  = k_ws + 3145728;          // (B,H,DH,T) bf16
    unsigned short* ctxT  = v_ws + 3145728;          // (B,T,D) bf16  [= xb alias]
    unsigned short* xb    = ctxT;                    // x bf16 [4096][768] (pre-attn)
    unsigned short* projb = ctxT + 3145728;          // (H,P,DH) bf16
    float* biascp = (float*)(projb + 393216);        // (H,P) f32
    unsigned short* WqkvT = (unsigned short*)(biascp + 6144);  // [2304][768] bf16
    unsigned short* WhT   = WqkvT + 1769472;         // [768][768] bf16

    cvt_b<<<dim3(1536), 256, 0, stream>>>(x, xb, 393216);
    transp_b<<<dim3(2304 / 32, 768 / 32), 256, 0, stream>>>(Wqkv, WqkvT, 768, 2304);
    transp_b<<<dim3(768 / 32, 768 / 32), 256, 0, stream>>>(Wh, WhT, 768, 768);

    gemm128<0><<<dim3(2304 / 128, 4096 / 128), 256, 0, stream>>>(
        xb, WqkvT, bqkv, q_ws, kout, vout, k_ws, v_ws, 768);
    gemm_mfma<1><<<dim3(768 / 64, 512 / 64), 256, 0, stream>>>(
        rpe, nullptr, Wp, bp, projb, nullptr, nullptr, 768, 768, 768);
    biascp_kernel<<<dim3(12), 256, 0, stream>>>(rcb, rpb, projb, biascp);
    attn_mfma<<<dim3(8, 96), 128, 0, stream>>>(
        q_ws, k_ws, v_ws, projb, biascp, ctxT);
    gemm128<2><<<dim3(768 / 128, 4096 / 128), 256, 0, stream>>>(
        ctxT, WhT, bh, nullptr, out, nullptr, nullptr, nullptr, 768);
}

// Round 4
// 239.345 us; speedup vs baseline: 1.7071x; 1.0091x over previous
//
#include <hip/hip_runtime.h>
#include <hip/hip_bf16.h>

// SelfMaskedAttention (Transformer-XL rel-pos), B=8 T=512 D=768 H=12 DH=64.
// R14: gemm128 gets a 2-phase double-buffered K-loop (T3 minimum recipe):
// issue next tile's global_load_lds BEFORE computing current tile, one raw
// s_barrier + vmcnt(0) per K-step. Hides global->LDS latency under MFMA
// (previous structure drained vmcnt before every MFMA phase -> 10% MfmaUtil
// at 2.25 waves/SIMD). Attention (R13 paired-tile balance) unchanged.

#define NT 512
#define ND 768
#define NH 12

typedef short short4_t __attribute__((ext_vector_type(4)));
typedef short short8_t __attribute__((ext_vector_type(8)));
typedef float float4_t __attribute__((ext_vector_type(4)));

__device__ __forceinline__ float b2f(unsigned short u) {
    union { unsigned int i; float f; } x; x.i = ((unsigned int)u) << 16; return x.f;
}
__device__ __forceinline__ unsigned short f2b(float f) {
    union { float f; unsigned int i; } x; x.f = f;
    unsigned int i = x.i;
    i += 0x7fffu + ((i >> 16) & 1u);   // RNE
    return (unsigned short)(i >> 16);
}

// ---------------- pre-pass: fp32 -> bf16 elementwise ----------------
__global__ __launch_bounds__(256) void cvt_b(const float* __restrict__ in,
                                             unsigned short* __restrict__ out, int n8)
{
    const int i = blockIdx.x * 256 + threadIdx.x;
    if (i >= n8) return;
    const float* s = in + (size_t)i * 8;
    float4_t f0 = *(const float4_t*)s;
    float4_t f1 = *(const float4_t*)(s + 4);
    union { short8_t v; unsigned short u[8]; } pk;
    pk.u[0] = f2b(f0[0]); pk.u[1] = f2b(f0[1]); pk.u[2] = f2b(f0[2]); pk.u[3] = f2b(f0[3]);
    pk.u[4] = f2b(f1[0]); pk.u[5] = f2b(f1[1]); pk.u[6] = f2b(f1[2]); pk.u[7] = f2b(f1[3]);
    *(short8_t*)&out[(size_t)i * 8] = pk.v;
}

// ---------------- pre-pass: W [K][N] fp32 -> WT [N][K] bf16 (32x32 tiles) ----
__global__ __launch_bounds__(256) void transp_b(const float* __restrict__ in,
                                                unsigned short* __restrict__ out,
                                                int K, int N)
{
    __shared__ float t[32][33];
    const int k0 = blockIdx.y * 32;
    const int n0 = blockIdx.x * 32;
    const int r  = threadIdx.x >> 3;
    const int c  = (threadIdx.x & 7) * 4;
    float4_t v = *(const float4_t*)&in[(size_t)(k0 + r) * N + n0 + c];
    t[r][c + 0] = v[0]; t[r][c + 1] = v[1]; t[r][c + 2] = v[2]; t[r][c + 3] = v[3];
    __syncthreads();
    union { short4_t v; unsigned short u[4]; } pk;
    pk.u[0] = f2b(t[c + 0][r]);
    pk.u[1] = f2b(t[c + 1][r]);
    pk.u[2] = f2b(t[c + 2][r]);
    pk.u[3] = f2b(t[c + 3][r]);
    *(short4_t*)&out[(size_t)(n0 + r) * K + k0 + c] = pk.v;
}

// ---------------- 128x128-tile MFMA GEMM, 2-phase double-buffered ----------------
// A [M][K] bf16 row-major, BT [N][K] bf16 row-major. 256 thr = 4 waves,
// wave quadrant 64x64 (acc[4][4]). BK=32. Next K-step staged via
// global_load_lds width=16 while current computes; 1 barrier + vmcnt(0)/step.
template <int MODE>   // 0: QKV scatter epilogue, 2: plain fp32 [M][N]
__global__ __launch_bounds__(256) void gemm128(
    const unsigned short* __restrict__ A, const unsigned short* __restrict__ BT,
    const float* __restrict__ biasf,
    unsigned short* __restrict__ ob0, float* __restrict__ o1, float* __restrict__ o2,
    unsigned short* __restrict__ sh1, unsigned short* __restrict__ sh2,
    int K)
{
    __shared__ __attribute__((aligned(16))) unsigned short Al[2][128 * 32];
    __shared__ __attribute__((aligned(16))) unsigned short Bl[2][128 * 32];

    const int tid  = threadIdx.x;
    const int m0   = blockIdx.y * 128;
    const int n0   = blockIdx.x * 128;
    const int wave = tid >> 6;
    const int lane = tid & 63;
    const int lm   = lane & 15;
    const int quad = lane >> 4;
    const int wr   = (wave >> 1) * 64;
    const int wc   = (wave & 1) * 64;

    float4_t acc[4][4];
#pragma unroll
    for (int mt = 0; mt < 4; ++mt)
#pragma unroll
        for (int nt = 0; nt < 4; ++nt)
#pragma unroll
            for (int r = 0; r < 4; ++r) acc[mt][nt][r] = 0.f;

    const unsigned short* ap = A  + (size_t)(m0 + (tid >> 2)) * K + (tid & 3) * 8;
    const unsigned short* bp = BT + (size_t)(n0 + (tid >> 2)) * K + (tid & 3) * 8;
    const size_t rstep = (size_t)64 * K;

    // stage K-step at byte offset k0 into buffer bi (wave-uniform LDS base;
    // HW scatters lane*16B). Covers rows tid>>2 (+64), cols (tid&3)*8 (+8).
    auto stage = [&](int bi, int k0) {
        unsigned short* al0 = Al[bi] + wave * 512;
        unsigned short* bl0 = Bl[bi] + wave * 512;
        __builtin_amdgcn_global_load_lds(
            (const __attribute__((address_space(1))) void*)(ap + k0),
            (__attribute__((address_space(3))) void*)al0, 16, 0, 0);
        __builtin_amdgcn_global_load_lds(
            (const __attribute__((address_space(1))) void*)(ap + rstep + k0),
            (__attribute__((address_space(3))) void*)(al0 + 2048), 16, 0, 0);
        __builtin_amdgcn_global_load_lds(
            (const __attribute__((address_space(1))) void*)(bp + k0),
            (__attribute__((address_space(3))) void*)bl0, 16, 0, 0);
        __builtin_amdgcn_global_load_lds(
            (const __attribute__((address_space(1))) void*)(bp + rstep + k0),
            (__attribute__((address_space(3))) void*)(bl0 + 2048), 16, 0, 0);
    };

    // prologue: fill buffer 0
    stage(0, 0);
    asm volatile("s_waitcnt vmcnt(0)" ::: "memory");
    __builtin_amdgcn_s_barrier();

    int cur = 0;
    for (int k0 = 0; k0 < K; k0 += 32) {
        if (k0 + 32 < K) stage(cur ^ 1, k0 + 32);   // prefetch next (overlaps MFMA)

        short8_t af[4], bf[4];
#pragma unroll
        for (int mt = 0; mt < 4; ++mt)
            af[mt] = *(const short8_t*)&Al[cur][(wr + mt * 16 + lm) * 32 + quad * 8];
#pragma unroll
        for (int nt = 0; nt < 4; ++nt)
            bf[nt] = *(const short8_t*)&Bl[cur][(wc + nt * 16 + lm) * 32 + quad * 8];
#pragma unroll
        for (int mt = 0; mt < 4; ++mt)
#pragma unroll
            for (int nt = 0; nt < 4; ++nt)
                acc[mt][nt] = __builtin_amdgcn_mfma_f32_16x16x32_bf16(af[mt], bf[nt], acc[mt][nt], 0, 0, 0);

        // drain prefetch (issued before MFMA -> latency already hidden), sync
        asm volatile("s_waitcnt vmcnt(0)" ::: "memory");
        __builtin_amdgcn_s_barrier();
        cur ^= 1;
    }

#pragma unroll
    for (int nt = 0; nt < 4; ++nt) {
        const int gcol = n0 + wc + nt * 16 + lm;
        const float bv = biasf[gcol];
#pragma unroll
        for (int mt = 0; mt < 4; ++mt) {
#pragma unroll
            for (int r = 0; r < 4; ++r) {
                const int grow = m0 + wr + mt * 16 + quad * 4 + r;
                const float val = acc[mt][nt][r] + bv;
                if (MODE == 0) {
                    int b = grow >> 9, t = grow & 511;
                    int sec = gcol / 768;
                    int cc = gcol - sec * 768;
                    int h = cc >> 6, d = cc & 63;
                    if (sec == 0) {
                        ob0[((size_t)((b * NH + h) * NT + t)) * 64 + d] = f2b(val);
                    } else if (sec == 1) {
                        o1[((size_t)((b * NH + h) * 64 + d)) * NT + t] = val;
                        sh1[((size_t)((b * NH + h) * NT + t)) * 64 + d] = f2b(val);
                    } else {
                        o2[((size_t)((b * NH + h) * NT + t)) * 64 + d] = val;
                        sh2[((size_t)((b * NH + h) * 64 + d)) * NT + t] = f2b(val);
                    }
                } else {
                    o1[(size_t)grow * ND + gcol] = val;
                }
            }
        }
    }
}

// ---------------- legacy 64x64 GEMM (MODE 1: proj) ----------------
template <int MODE>
__global__ __launch_bounds__(256) void gemm_mfma(
    const float* __restrict__ Af, const unsigned short* __restrict__ Ab,
    const float* __restrict__ Bw, const float* __restrict__ biasf,
    unsigned short* __restrict__ ob0, float* __restrict__ o1, float* __restrict__ o2,
    int N, int K, int ldb)
{
    __shared__ unsigned short Al[64][40];
    __shared__ unsigned short Bl[64][40];

    const int tid  = threadIdx.x;
    const int m0   = blockIdx.y * 64;
    const int n0   = blockIdx.x * 64;
    const int wave = tid >> 6;
    const int lane = tid & 63;
    const int lm   = lane & 15;
    const int quad = lane >> 4;
    const int koff = quad * 8;

    float4_t acc[4];
#pragma unroll
    for (int j = 0; j < 4; ++j)
#pragma unroll
        for (int r = 0; r < 4; ++r) acc[j][r] = 0.0f;

    const int arow = tid >> 2;
    const int acg  = (tid & 3) * 8;
    const int bk   = tid & 31;
    const int bg   = tid >> 5;

    for (int k0 = 0; k0 < K; k0 += 32) {
        {
            const float* src = &Af[(size_t)(m0 + arow) * K + k0 + acg];
            float4_t f0 = *(const float4_t*)src;
            float4_t f1 = *(const float4_t*)(src + 4);
            union { short8_t v; unsigned short u[8]; } pk;
            pk.u[0] = f2b(f0[0]); pk.u[1] = f2b(f0[1]); pk.u[2] = f2b(f0[2]); pk.u[3] = f2b(f0[3]);
            pk.u[4] = f2b(f1[0]); pk.u[5] = f2b(f1[1]); pk.u[6] = f2b(f1[2]); pk.u[7] = f2b(f1[3]);
            *(short8_t*)&Al[arow][acg] = pk.v;
        }
        {
            const float* src = &Bw[(size_t)(k0 + bk) * ldb + n0 + bg * 8];
            float4_t f0 = *(const float4_t*)src;
            float4_t f1 = *(const float4_t*)(src + 4);
            Bl[bg * 8 + 0][bk] = f2b(f0[0]); Bl[bg * 8 + 1][bk] = f2b(f0[1]);
            Bl[bg * 8 + 2][bk] = f2b(f0[2]); Bl[bg * 8 + 3][bk] = f2b(f0[3]);
            Bl[bg * 8 + 4][bk] = f2b(f1[0]); Bl[bg * 8 + 5][bk] = f2b(f1[1]);
            Bl[bg * 8 + 6][bk] = f2b(f1[2]); Bl[bg * 8 + 7][bk] = f2b(f1[3]);
        }
        __syncthreads();

        short8_t af = *(const short8_t*)&Al[wave * 16 + lm][koff];
#pragma unroll
        for (int j = 0; j < 4; ++j) {
            short8_t bf = *(const short8_t*)&Bl[j * 16 + lm][koff];
            acc[j] = __builtin_amdgcn_mfma_f32_16x16x32_bf16(af, bf, acc[j], 0, 0, 0);
        }
        __syncthreads();
    }

#pragma unroll
    for (int j = 0; j < 4; ++j) {
        const int gcol = n0 + j * 16 + lm;
        const float bv = biasf[gcol];
#pragma unroll
        for (int r = 0; r < 4; ++r) {
            const int grow = m0 + wave * 16 + quad * 4 + r;
            const float val = acc[j][r] + bv;
            if (MODE == 1) {
                int h = gcol >> 6, d = gcol & 63;
                ob0[((size_t)(h * NT + grow)) * 64 + d] = f2b(val);   // projb bf16
            }
        }
    }
}

// ---------------- bias_cp (reads bf16 projb) ----------------
__global__ __launch_bounds__(256) void biascp_kernel(
    const float* __restrict__ rcb, const float* __restrict__ rpb,
    const unsigned short* __restrict__ projb, float* __restrict__ biascp)
{
    __shared__ float cb[64];
    const int h = blockIdx.x;
    const int tid = threadIdx.x;
    if (tid < 64) cb[tid] = rcb[h * 64 + tid] + rpb[h * 64 + tid];
    __syncthreads();
    for (int p = tid; p < NT; p += 256) {
        const unsigned short* pr = &projb[((size_t)(h * NT + p)) * 64];
        float s = 0.f;
#pragma unroll 8
        for (int d = 0; d < 64; ++d) s += b2f(pr[d]) * cb[d];
        biascp[h * NT + p] = s;
    }
}

// ---------------- MFMA attention: grid (8, 96), 128 thr, paired 32-row tiles --
__global__ __launch_bounds__(128) void attn_mfma(
    const unsigned short* __restrict__ q_ws, const unsigned short* __restrict__ k_ws,
    const unsigned short* __restrict__ v_ws, const unsigned short* __restrict__ projb,
    const float* __restrict__ biascp, unsigned short* __restrict__ ctxT)
{
    __shared__ unsigned short Kt[64][72];    // [s][d] bf16
    __shared__ unsigned short Vt[64][72];    // [d][s] bf16
    __shared__ unsigned short pP[96][72];    // [p][d] bf16 (tile rel-window)
    __shared__ float          Rl[2][16][84]; // per-wave R + bias, f32
    __shared__ unsigned short esl[2][16][72];// per-wave e bf16 (PV A-operand)

    const int tid   = threadIdx.x;
    const int y     = blockIdx.y;       // b*H + h
    const int h     = y % NH;
    const int b     = y / NH;
    const int pairi = blockIdx.x;       // 0..7
    const int wave  = tid >> 6;
    const int lane  = tid & 63;
    const int lm    = lane & 15;
    const int quad  = lane >> 4;
    const int koff  = quad * 8;

    const int sr = tid >> 1;           // staging row 0..63
    const int sc = (tid & 1) * 32;     // 32-short chunk

    for (int c = 0; c < 2; ++c) {
        const int ti  = c ? pairi : (15 - pairi);
        const int tb0 = ti * 32;
        const int tw0 = tb0 + wave * 16;
        const int nst = (tb0 >> 6) + 1;

        short8_t aq[2];
        aq[0] = *(const short8_t*)&q_ws[((size_t)(y * NT + tw0 + lm)) * 64 + koff];
        aq[1] = *(const short8_t*)&q_ws[((size_t)(y * NT + tw0 + lm)) * 64 + koff + 32];

        float4_t ctxacc[4];
#pragma unroll
        for (int j = 0; j < 4; ++j)
#pragma unroll
            for (int r = 0; r < 4; ++r) ctxacc[j][r] = 0.f;
        float esum[4] = {0.f, 0.f, 0.f, 0.f};

        for (int st = 0; st < nst; ++st) {
            const int s0      = st * 64;
            const int plo_blk = max(0, tb0 - s0 - 63);
            const int cnt_blk = tb0 + 31 - s0 - plo_blk + 1;   // 32..95
            if (c | st) __syncthreads();
            {   // ---- stage K^T [s][d], V^T [d][s], proj window — short8 copies
                const unsigned short* ks = &k_ws[((size_t)(y * NT + s0 + sr)) * 64 + sc];
                *(short8_t*)&Kt[sr][sc]      = *(const short8_t*)ks;
                *(short8_t*)&Kt[sr][sc + 8]  = *(const short8_t*)(ks + 8);
                *(short8_t*)&Kt[sr][sc + 16] = *(const short8_t*)(ks + 16);
                *(short8_t*)&Kt[sr][sc + 24] = *(const short8_t*)(ks + 24);
                const unsigned short* vs = &v_ws[((size_t)(y * 64 + sr)) * NT + s0 + sc];
                *(short8_t*)&Vt[sr][sc]      = *(const short8_t*)vs;
                *(short8_t*)&Vt[sr][sc + 8]  = *(const short8_t*)(vs + 8);
                *(short8_t*)&Vt[sr][sc + 16] = *(const short8_t*)(vs + 16);
                *(short8_t*)&Vt[sr][sc + 24] = *(const short8_t*)(vs + 24);
                for (int p = tid; p < cnt_blk; p += 128) {
                    const unsigned short* ps = &projb[((size_t)(h * NT + plo_blk + p)) * 64];
                    *(short8_t*)&pP[p][0]  = *(const short8_t*)ps;
                    *(short8_t*)&pP[p][8]  = *(const short8_t*)(ps + 8);
                    *(short8_t*)&pP[p][16] = *(const short8_t*)(ps + 16);
                    *(short8_t*)&pP[p][24] = *(const short8_t*)(ps + 24);
                    *(short8_t*)&pP[p][32] = *(const short8_t*)(ps + 32);
                    *(short8_t*)&pP[p][40] = *(const short8_t*)(ps + 40);
                    *(short8_t*)&pP[p][48] = *(const short8_t*)(ps + 48);
                    *(short8_t*)&pP[p][56] = *(const short8_t*)(ps + 56);
                }
            }
            __syncthreads();

            if (s0 <= tw0 + 15) {   // wave-uniform: wave has active s here
                const int plo_w = max(0, tw0 - s0 - 63);
                const int pbase = plo_w - plo_blk;            // 0 or 16
                const int cntw  = tw0 + 15 - s0 - plo_w + 1;  // 16..79
                const int jmax  = min(3, (tw0 + 15 - s0) >> 4);
                const int jpmax = (cntw - 1) >> 4;            // <= 4

                // ---- QK^T
                float4_t accQK[4];
#pragma unroll
                for (int j = 0; j < 4; ++j)
#pragma unroll
                    for (int r = 0; r < 4; ++r) accQK[j][r] = 0.f;
                for (int j = 0; j <= jmax; ++j) {
                    short8_t bk0 = *(const short8_t*)&Kt[j * 16 + lm][koff];
                    short8_t bk1 = *(const short8_t*)&Kt[j * 16 + lm][koff + 32];
                    accQK[j] = __builtin_amdgcn_mfma_f32_16x16x32_bf16(aq[0], bk0, accQK[j], 0, 0, 0);
                    accQK[j] = __builtin_amdgcn_mfma_f32_16x16x32_bf16(aq[1], bk1, accQK[j], 0, 0, 0);
                }
                // ---- R = Q . proj^T, bias folded at write
                for (int j = 0; j <= jpmax; ++j) {
                    short8_t bp0 = *(const short8_t*)&pP[pbase + j * 16 + lm][koff];
                    short8_t bp1 = *(const short8_t*)&pP[pbase + j * 16 + lm][koff + 32];
                    float4_t accR;
#pragma unroll
                    for (int r = 0; r < 4; ++r) accR[r] = 0.f;
                    accR = __builtin_amdgcn_mfma_f32_16x16x32_bf16(aq[0], bp0, accR, 0, 0, 0);
                    accR = __builtin_amdgcn_mfma_f32_16x16x32_bf16(aq[1], bp1, accR, 0, 0, 0);
                    const int p = j * 16 + lm;
                    const float bv = biascp[h * NT + min(plo_w + p, NT - 1)];
#pragma unroll
                    for (int r = 0; r < 4; ++r) Rl[wave][quad * 4 + r][p] = accR[r] + bv;
                }
                asm volatile("" ::: "memory");   // order Rl write -> gather (same wave)

                // ---- e = exp((QK + R[t][t-s-plo_w]) / 9) * mask
#pragma unroll
                for (int j = 0; j < 4; ++j) {
                    const int s_g = s0 + j * 16 + lm;
#pragma unroll
                    for (int r = 0; r < 4; ++r) {
                        const int t_g = tw0 + quad * 4 + r;
                        float e = 0.f;
                        if (s_g <= t_g) {
                            const int p = t_g - s_g - plo_w;
                            e = __expf(fminf((accQK[j][r] + Rl[wave][quad * 4 + r][p]) * (1.f / 9.f), 60.f));
                        }
                        esl[wave][quad * 4 + r][j * 16 + lm] = f2b(e);
                        esum[r] += e;
                    }
                }
                asm volatile("" ::: "memory");   // order esl write -> A-frag read

                // ---- P.V: ctx[t][d] += e[t][s] * V[s][d]
                short8_t ae0 = *(const short8_t*)&esl[wave][lm][koff];
                short8_t ae1 = *(const short8_t*)&esl[wave][lm][koff + 32];
#pragma unroll
                for (int j = 0; j < 4; ++j) {
                    short8_t bv0 = *(const short8_t*)&Vt[j * 16 + lm][koff];
                    short8_t bv1 = *(const short8_t*)&Vt[j * 16 + lm][koff + 32];
                    ctxacc[j] = __builtin_amdgcn_mfma_f32_16x16x32_bf16(ae0, bv0, ctxacc[j], 0, 0, 0);
                    ctxacc[j] = __builtin_amdgcn_mfma_f32_16x16x32_bf16(ae1, bv1, ctxacc[j], 0, 0, 0);
                }
            }
        }

        // ---- per-tile epilogue: reduce esum within quad, normalize, store
        float rcpv[4];
#pragma unroll
        for (int r = 0; r < 4; ++r) {
            float v = esum[r];
            v += __shfl_xor(v, 1); v += __shfl_xor(v, 2);
            v += __shfl_xor(v, 4); v += __shfl_xor(v, 8);
            rcpv[r] = 1.f / (v + 2.f);
        }
#pragma unroll
        for (int j = 0; j < 4; ++j) {
            const int d = j * 16 + lm;
#pragma unroll
            for (int r = 0; r < 4; ++r) {
                const int t = tw0 + quad * 4 + r;
                ctxT[((size_t)(b * NT + t)) * ND + d * NH + h] = f2b(ctxacc[j][r] * rcpv[r]);
            }
        }
    }
}

extern "C" void kernel_launch(void* const* d_in, const int* in_sizes, int n_in,
                              void* d_out, int out_size, void* d_ws, size_t ws_size,
                              hipStream_t stream)
{
    const float* x    = (const float*)d_in[0];
    const float* rpe  = (const float*)d_in[1];
    const float* rcb  = (const float*)d_in[2];
    const float* rpb  = (const float*)d_in[3];
    const float* Wqkv = (const float*)d_in[4];
    const float* bqkv = (const float*)d_in[5];
    const float* Wh   = (const float*)d_in[6];
    const float* bh   = (const float*)d_in[7];
    const float* Wp   = (const float*)d_in[8];
    const float* bp   = (const float*)d_in[9];

    float* out  = (float*)d_out;             // (B,T,D) fp32
    float* kout = out + 3145728;             // (B,H,DH,T) fp32
    float* vout = out + 6291456;             // (B,H,T,DH) fp32

    unsigned short* q_ws  = (unsigned short*)d_ws;   // (B,H,T,DH) bf16
    unsigned short* k_ws  = q_ws + 3145728;          // (B,H,T,DH) bf16
    unsigned short* v_ws  = k_ws + 3145728;          // (B,H,DH,T) bf16
    unsigned short* ctxT  = v_ws + 3145728;          // (B,T,D) bf16  [= xb alias]
    unsigned short* xb    = ctxT;                    // x bf16 [4096][768] (pre-attn)
    unsigned short* projb = ctxT + 3145728;          // (H,P,DH) bf16
    float* biascp = (float*)(projb + 393216);        // (H,P) f32
    unsigned short* WqkvT = (unsigned short*)(biascp + 6144);  // [2304][768] bf16
    unsigned short* WhT   = WqkvT + 1769472;         // [768][768] bf16

    cvt_b<<<dim3(1536), 256, 0, stream>>>(x, xb, 393216);
    transp_b<<<dim3(2304 / 32, 768 / 32), 256, 0, stream>>>(Wqkv, WqkvT, 768, 2304);
    transp_b<<<dim3(768 / 32, 768 / 32), 256, 0, stream>>>(Wh, WhT, 768, 768);

    gemm128<0><<<dim3(2304 / 128, 4096 / 128), 256, 0, stream>>>(
        xb, WqkvT, bqkv, q_ws, kout, vout, k_ws, v_ws, 768);
    gemm_mfma<1><<<dim3(768 / 64, 512 / 64), 256, 0, stream>>>(
        rpe, nullptr, Wp, bp, projb, nullptr, nullptr, 768, 768, 768);
    biascp_kernel<<<dim3(12), 256, 0, stream>>>(rcb, rpb, projb, biascp);
    attn_mfma<<<dim3(8, 96), 128, 0, stream>>>(
        q_ws, k_ws, v_ws, projb, biascp, ctxT);
    gemm128<2><<<dim3(768 / 128, 4096 / 128), 256, 0, stream>>>(
        ctxT, WhT, bh, nullptr, out, nullptr, nullptr, nullptr, 768);
}

// Round 5
// 239.001 us; speedup vs baseline: 1.7095x; 1.0014x over previous
//
#include <hip/hip_runtime.h>
#include <hip/hip_bf16.h>

// SelfMaskedAttention (Transformer-XL rel-pos), B=8 T=512 D=768 H=12 DH=64.
// R15: (1) gemm128 K-loop -> 3-deep pipeline with COUNTED vmcnt (T4): triple
// LDS buffer, stage k+2 each iter, s_waitcnt vmcnt(4) (never 0 mid-loop) so
// every load gets a full K-step of compute to land. (2) fewer dispatches:
// cvt+2 transposes fused into prep; biascp folded into gemm_proj epilogue.
// Attention (R13 paired-tile balance) unchanged.

#define NT 512
#define ND 768
#define NH 12

typedef short short4_t __attribute__((ext_vector_type(4)));
typedef short short8_t __attribute__((ext_vector_type(8)));
typedef float float4_t __attribute__((ext_vector_type(4)));

__device__ __forceinline__ float b2f(unsigned short u) {
    union { unsigned int i; float f; } x; x.i = ((unsigned int)u) << 16; return x.f;
}
__device__ __forceinline__ unsigned short f2b(float f) {
    union { float f; unsigned int i; } x; x.f = f;
    unsigned int i = x.i;
    i += 0x7fffu + ((i >> 16) & 1u);   // RNE
    return (unsigned short)(i >> 16);
}

// ---------------- fused pre-pass: cvt x->bf16, transpose Wqkv & Wh ----------
// blocks [0,1536): cvt; [1536,3264): Wqkv 32x32 transp; [3264,3840): Wh.
__global__ __launch_bounds__(256) void prep(
    const float* __restrict__ x, unsigned short* __restrict__ xb,
    const float* __restrict__ Wqkv, unsigned short* __restrict__ WqkvT,
    const float* __restrict__ Wh, unsigned short* __restrict__ WhT)
{
    __shared__ float t[32][33];
    const int bid = blockIdx.x;
    const int tid = threadIdx.x;

    if (bid < 1536) {               // ---- cvt: x (fp32) -> xb (bf16), 8/thread
        const int i = bid * 256 + tid;
        const float* s = x + (size_t)i * 8;
        float4_t f0 = *(const float4_t*)s;
        float4_t f1 = *(const float4_t*)(s + 4);
        union { short8_t v; unsigned short u[8]; } pk;
        pk.u[0] = f2b(f0[0]); pk.u[1] = f2b(f0[1]); pk.u[2] = f2b(f0[2]); pk.u[3] = f2b(f0[3]);
        pk.u[4] = f2b(f1[0]); pk.u[5] = f2b(f1[1]); pk.u[6] = f2b(f1[2]); pk.u[7] = f2b(f1[3]);
        *(short8_t*)&xb[(size_t)i * 8] = pk.v;
        return;
    }
    // ---- transpose path: W [K][N] fp32 -> WT [N][K] bf16, 32x32 tile
    const float* in; unsigned short* out; int K, N, k0, n0;
    if (bid < 3264) {
        const int tt = bid - 1536;      // Wqkv: N=2304 (72 n-tiles) x K=768 (24)
        in = Wqkv; out = WqkvT; K = 768; N = 2304;
        n0 = (tt % 72) * 32; k0 = (tt / 72) * 32;
    } else {
        const int tt = bid - 3264;      // Wh: N=768 (24) x K=768 (24)
        in = Wh; out = WhT; K = 768; N = 768;
        n0 = (tt % 24) * 32; k0 = (tt / 24) * 32;
    }
    const int r = tid >> 3;
    const int c = (tid & 7) * 4;
    float4_t v = *(const float4_t*)&in[(size_t)(k0 + r) * N + n0 + c];
    t[r][c + 0] = v[0]; t[r][c + 1] = v[1]; t[r][c + 2] = v[2]; t[r][c + 3] = v[3];
    __syncthreads();
    union { short4_t v; unsigned short u[4]; } pk;
    pk.u[0] = f2b(t[c + 0][r]);
    pk.u[1] = f2b(t[c + 1][r]);
    pk.u[2] = f2b(t[c + 2][r]);
    pk.u[3] = f2b(t[c + 3][r]);
    *(short4_t*)&out[(size_t)(n0 + r) * K + k0 + c] = pk.v;
}

// ---------------- 128x128-tile MFMA GEMM, 3-deep counted-vmcnt pipeline ------
// A [M][K] bf16 row-major, BT [N][K] bf16 row-major. 256 thr = 4 waves,
// wave quadrant 64x64 (acc[4][4]). BK=32. Buffers cycle mod 3; each iter
// waits vmcnt(4) (own wave's oldest 4 loads = current buf), barriers, then
// stages K-step i+2. Loads get ~1 full K-step + barrier of cover; vmcnt
// drains to 0 only on the last iteration.
template <int MODE>   // 0: QKV scatter epilogue, 2: plain fp32 [M][N]
__global__ __launch_bounds__(256) void gemm128(
    const unsigned short* __restrict__ A, const unsigned short* __restrict__ BT,
    const float* __restrict__ biasf,
    unsigned short* __restrict__ ob0, float* __restrict__ o1, float* __restrict__ o2,
    unsigned short* __restrict__ sh1, unsigned short* __restrict__ sh2,
    int K)
{
    __shared__ __attribute__((aligned(16))) unsigned short Al[3][128 * 32];
    __shared__ __attribute__((aligned(16))) unsigned short Bl[3][128 * 32];

    const int tid  = threadIdx.x;
    const int m0   = blockIdx.y * 128;
    const int n0   = blockIdx.x * 128;
    const int wave = tid >> 6;
    const int lane = tid & 63;
    const int lm   = lane & 15;
    const int quad = lane >> 4;
    const int wr   = (wave >> 1) * 64;
    const int wc   = (wave & 1) * 64;

    float4_t acc[4][4];
#pragma unroll
    for (int mt = 0; mt < 4; ++mt)
#pragma unroll
        for (int nt = 0; nt < 4; ++nt)
#pragma unroll
            for (int r = 0; r < 4; ++r) acc[mt][nt][r] = 0.f;

    const unsigned short* ap = A  + (size_t)(m0 + (tid >> 2)) * K + (tid & 3) * 8;
    const unsigned short* bp = BT + (size_t)(n0 + (tid >> 2)) * K + (tid & 3) * 8;
    const size_t rstep = (size_t)64 * K;

    auto stage = [&](int bi, int k0) {
        unsigned short* al0 = &Al[bi][0] + wave * 512;
        unsigned short* bl0 = &Bl[bi][0] + wave * 512;
        __builtin_amdgcn_global_load_lds(
            (const __attribute__((address_space(1))) void*)(ap + k0),
            (__attribute__((address_space(3))) void*)al0, 16, 0, 0);
        __builtin_amdgcn_global_load_lds(
            (const __attribute__((address_space(1))) void*)(ap + rstep + k0),
            (__attribute__((address_space(3))) void*)(al0 + 2048), 16, 0, 0);
        __builtin_amdgcn_global_load_lds(
            (const __attribute__((address_space(1))) void*)(bp + k0),
            (__attribute__((address_space(3))) void*)bl0, 16, 0, 0);
        __builtin_amdgcn_global_load_lds(
            (const __attribute__((address_space(1))) void*)(bp + rstep + k0),
            (__attribute__((address_space(3))) void*)(bl0 + 2048), 16, 0, 0);
    };

    // prologue: stage K-steps 0 and 1 (8 loads in flight)
    stage(0, 0);
    stage(1, 32);

    int cur = 0;
    for (int k0 = 0; k0 < K; k0 += 32) {
        // wait own wave's oldest 4 loads (current buf); keep next buf's in flight
        if (k0 + 32 < K) asm volatile("s_waitcnt vmcnt(4)" ::: "memory");
        else             asm volatile("s_waitcnt vmcnt(0)" ::: "memory");
        __builtin_amdgcn_s_barrier();        // all waves' loads for cur buf done
        __builtin_amdgcn_sched_barrier(0);   // pin: no motion above the barrier

        if (k0 + 64 < K) stage((cur + 2) % 3, k0 + 64);   // overwrites buf (i-1)

        short8_t af[4], bf[4];
#pragma unroll
        for (int mt = 0; mt < 4; ++mt)
            af[mt] = *(const short8_t*)&Al[cur][(wr + mt * 16 + lm) * 32 + quad * 8];
#pragma unroll
        for (int nt = 0; nt < 4; ++nt)
            bf[nt] = *(const short8_t*)&Bl[cur][(wc + nt * 16 + lm) * 32 + quad * 8];
#pragma unroll
        for (int mt = 0; mt < 4; ++mt)
#pragma unroll
            for (int nt = 0; nt < 4; ++nt)
                acc[mt][nt] = __builtin_amdgcn_mfma_f32_16x16x32_bf16(af[mt], bf[nt], acc[mt][nt], 0, 0, 0);

        cur = (cur + 1) % 3;
        // no end-of-iter barrier: next iter's vmcnt+barrier gates buffer reuse
    }

#pragma unroll
    for (int nt = 0; nt < 4; ++nt) {
        const int gcol = n0 + wc + nt * 16 + lm;
        const float bv = biasf[gcol];
#pragma unroll
        for (int mt = 0; mt < 4; ++mt) {
#pragma unroll
            for (int r = 0; r < 4; ++r) {
                const int grow = m0 + wr + mt * 16 + quad * 4 + r;
                const float val = acc[mt][nt][r] + bv;
                if (MODE == 0) {
                    int b = grow >> 9, t = grow & 511;
                    int sec = gcol / 768;
                    int cc = gcol - sec * 768;
                    int h = cc >> 6, d = cc & 63;
                    if (sec == 0) {
                        ob0[((size_t)((b * NH + h) * NT + t)) * 64 + d] = f2b(val);
                    } else if (sec == 1) {
                        o1[((size_t)((b * NH + h) * 64 + d)) * NT + t] = val;
                        sh1[((size_t)((b * NH + h) * NT + t)) * 64 + d] = f2b(val);
                    } else {
                        o2[((size_t)((b * NH + h) * NT + t)) * 64 + d] = val;
                        sh2[((size_t)((b * NH + h) * 64 + d)) * NT + t] = f2b(val);
                    }
                } else {
                    o1[(size_t)grow * ND + gcol] = val;
                }
            }
        }
    }
}

// ---------------- proj GEMM (64x64) with fused biascp epilogue ----------------
// rpe (512x768) @ Wp + bp -> projb bf16 [H][P][DH]. Block (bx,by) covers head
// h=bx, rows m0..m0+63, all 64 d -> also emits biascp[h][p] = sum_d val*cb[d].
__global__ __launch_bounds__(256) void gemm_proj(
    const float* __restrict__ Af, const float* __restrict__ Bw,
    const float* __restrict__ biasf,
    const float* __restrict__ rcb, const float* __restrict__ rpb,
    unsigned short* __restrict__ projb, float* __restrict__ biascp)
{
    __shared__ unsigned short Al[64][40];
    __shared__ unsigned short Bl[64][40];

    const int tid  = threadIdx.x;
    const int m0   = blockIdx.y * 64;
    const int n0   = blockIdx.x * 64;
    const int wave = tid >> 6;
    const int lane = tid & 63;
    const int lm   = lane & 15;
    const int quad = lane >> 4;
    const int koff = quad * 8;
    const int K = 768, ldb = 768;

    float4_t acc[4];
#pragma unroll
    for (int j = 0; j < 4; ++j)
#pragma unroll
        for (int r = 0; r < 4; ++r) acc[j][r] = 0.0f;

    const int arow = tid >> 2;
    const int acg  = (tid & 3) * 8;
    const int bk   = tid & 31;
    const int bg   = tid >> 5;

    for (int k0 = 0; k0 < K; k0 += 32) {
        {
            const float* src = &Af[(size_t)(m0 + arow) * K + k0 + acg];
            float4_t f0 = *(const float4_t*)src;
            float4_t f1 = *(const float4_t*)(src + 4);
            union { short8_t v; unsigned short u[8]; } pk;
            pk.u[0] = f2b(f0[0]); pk.u[1] = f2b(f0[1]); pk.u[2] = f2b(f0[2]); pk.u[3] = f2b(f0[3]);
            pk.u[4] = f2b(f1[0]); pk.u[5] = f2b(f1[1]); pk.u[6] = f2b(f1[2]); pk.u[7] = f2b(f1[3]);
            *(short8_t*)&Al[arow][acg] = pk.v;
        }
        {
            const float* src = &Bw[(size_t)(k0 + bk) * ldb + n0 + bg * 8];
            float4_t f0 = *(const float4_t*)src;
            float4_t f1 = *(const float4_t*)(src + 4);
            Bl[bg * 8 + 0][bk] = f2b(f0[0]); Bl[bg * 8 + 1][bk] = f2b(f0[1]);
            Bl[bg * 8 + 2][bk] = f2b(f0[2]); Bl[bg * 8 + 3][bk] = f2b(f0[3]);
            Bl[bg * 8 + 4][bk] = f2b(f1[0]); Bl[bg * 8 + 5][bk] = f2b(f1[1]);
            Bl[bg * 8 + 6][bk] = f2b(f1[2]); Bl[bg * 8 + 7][bk] = f2b(f1[3]);
        }
        __syncthreads();

        short8_t af = *(const short8_t*)&Al[wave * 16 + lm][koff];
#pragma unroll
        for (int j = 0; j < 4; ++j) {
            short8_t bf = *(const short8_t*)&Bl[j * 16 + lm][koff];
            acc[j] = __builtin_amdgcn_mfma_f32_16x16x32_bf16(af, bf, acc[j], 0, 0, 0);
        }
        __syncthreads();
    }

    const int h = n0 >> 6;   // one head per n-tile (N=768 = 12 x 64)
    float cb4[4], part[4] = {0.f, 0.f, 0.f, 0.f};
#pragma unroll
    for (int j = 0; j < 4; ++j) {
        const int d = j * 16 + lm;
        cb4[j] = rcb[h * 64 + d] + rpb[h * 64 + d];
    }
#pragma unroll
    for (int j = 0; j < 4; ++j) {
        const int gcol = n0 + j * 16 + lm;
        const int d = gcol & 63;
        const float bv = biasf[gcol];
#pragma unroll
        for (int r = 0; r < 4; ++r) {
            const int grow = m0 + wave * 16 + quad * 4 + r;
            const float val = acc[j][r] + bv;
            projb[((size_t)(h * NT + grow)) * 64 + d] = f2b(val);
            part[r] += val * cb4[j];
        }
    }
#pragma unroll
    for (int r = 0; r < 4; ++r) {
        float v = part[r];
        v += __shfl_xor(v, 1); v += __shfl_xor(v, 2);
        v += __shfl_xor(v, 4); v += __shfl_xor(v, 8);
        if (lm == 0) biascp[h * NT + m0 + wave * 16 + quad * 4 + r] = v;
    }
}

// ---------------- MFMA attention: grid (8, 96), 128 thr, paired 32-row tiles --
__global__ __launch_bounds__(128) void attn_mfma(
    const unsigned short* __restrict__ q_ws, const unsigned short* __restrict__ k_ws,
    const unsigned short* __restrict__ v_ws, const unsigned short* __restrict__ projb,
    const float* __restrict__ biascp, unsigned short* __restrict__ ctxT)
{
    __shared__ unsigned short Kt[64][72];    // [s][d] bf16
    __shared__ unsigned short Vt[64][72];    // [d][s] bf16
    __shared__ unsigned short pP[96][72];    // [p][d] bf16 (tile rel-window)
    __shared__ float          Rl[2][16][84]; // per-wave R + bias, f32
    __shared__ unsigned short esl[2][16][72];// per-wave e bf16 (PV A-operand)

    const int tid   = threadIdx.x;
    const int y     = blockIdx.y;       // b*H + h
    const int h     = y % NH;
    const int b     = y / NH;
    const int pairi = blockIdx.x;       // 0..7
    const int wave  = tid >> 6;
    const int lane  = tid & 63;
    const int lm    = lane & 15;
    const int quad  = lane >> 4;
    const int koff  = quad * 8;

    const int sr = tid >> 1;           // staging row 0..63
    const int sc = (tid & 1) * 32;     // 32-short chunk

    for (int c = 0; c < 2; ++c) {
        const int ti  = c ? pairi : (15 - pairi);
        const int tb0 = ti * 32;
        const int tw0 = tb0 + wave * 16;
        const int nst = (tb0 >> 6) + 1;

        short8_t aq[2];
        aq[0] = *(const short8_t*)&q_ws[((size_t)(y * NT + tw0 + lm)) * 64 + koff];
        aq[1] = *(const short8_t*)&q_ws[((size_t)(y * NT + tw0 + lm)) * 64 + koff + 32];

        float4_t ctxacc[4];
#pragma unroll
        for (int j = 0; j < 4; ++j)
#pragma unroll
            for (int r = 0; r < 4; ++r) ctxacc[j][r] = 0.f;
        float esum[4] = {0.f, 0.f, 0.f, 0.f};

        for (int st = 0; st < nst; ++st) {
            const int s0      = st * 64;
            const int plo_blk = max(0, tb0 - s0 - 63);
            const int cnt_blk = tb0 + 31 - s0 - plo_blk + 1;   // 32..95
            if (c | st) __syncthreads();
            {   // ---- stage K^T [s][d], V^T [d][s], proj window — short8 copies
                const unsigned short* ks = &k_ws[((size_t)(y * NT + s0 + sr)) * 64 + sc];
                *(short8_t*)&Kt[sr][sc]      = *(const short8_t*)ks;
                *(short8_t*)&Kt[sr][sc + 8]  = *(const short8_t*)(ks + 8);
                *(short8_t*)&Kt[sr][sc + 16] = *(const short8_t*)(ks + 16);
                *(short8_t*)&Kt[sr][sc + 24] = *(const short8_t*)(ks + 24);
                const unsigned short* vs = &v_ws[((size_t)(y * 64 + sr)) * NT + s0 + sc];
                *(short8_t*)&Vt[sr][sc]      = *(const short8_t*)vs;
                *(short8_t*)&Vt[sr][sc + 8]  = *(const short8_t*)(vs + 8);
                *(short8_t*)&Vt[sr][sc + 16] = *(const short8_t*)(vs + 16);
                *(short8_t*)&Vt[sr][sc + 24] = *(const short8_t*)(vs + 24);
                for (int p = tid; p < cnt_blk; p += 128) {
                    const unsigned short* ps = &projb[((size_t)(h * NT + plo_blk + p)) * 64];
                    *(short8_t*)&pP[p][0]  = *(const short8_t*)ps;
                    *(short8_t*)&pP[p][8]  = *(const short8_t*)(ps + 8);
                    *(short8_t*)&pP[p][16] = *(const short8_t*)(ps + 16);
                    *(short8_t*)&pP[p][24] = *(const short8_t*)(ps + 24);
                    *(short8_t*)&pP[p][32] = *(const short8_t*)(ps + 32);
                    *(short8_t*)&pP[p][40] = *(const short8_t*)(ps + 40);
                    *(short8_t*)&pP[p][48] = *(const short8_t*)(ps + 48);
                    *(short8_t*)&pP[p][56] = *(const short8_t*)(ps + 56);
                }
            }
            __syncthreads();

            if (s0 <= tw0 + 15) {   // wave-uniform: wave has active s here
                const int plo_w = max(0, tw0 - s0 - 63);
                const int pbase = plo_w - plo_blk;            // 0 or 16
                const int cntw  = tw0 + 15 - s0 - plo_w + 1;  // 16..79
                const int jmax  = min(3, (tw0 + 15 - s0) >> 4);
                const int jpmax = (cntw - 1) >> 4;            // <= 4

                // ---- QK^T
                float4_t accQK[4];
#pragma unroll
                for (int j = 0; j < 4; ++j)
#pragma unroll
                    for (int r = 0; r < 4; ++r) accQK[j][r] = 0.f;
                for (int j = 0; j <= jmax; ++j) {
                    short8_t bk0 = *(const short8_t*)&Kt[j * 16 + lm][koff];
                    short8_t bk1 = *(const short8_t*)&Kt[j * 16 + lm][koff + 32];
                    accQK[j] = __builtin_amdgcn_mfma_f32_16x16x32_bf16(aq[0], bk0, accQK[j], 0, 0, 0);
                    accQK[j] = __builtin_amdgcn_mfma_f32_16x16x32_bf16(aq[1], bk1, accQK[j], 0, 0, 0);
                }
                // ---- R = Q . proj^T, bias folded at write
                for (int j = 0; j <= jpmax; ++j) {
                    short8_t bp0 = *(const short8_t*)&pP[pbase + j * 16 + lm][koff];
                    short8_t bp1 = *(const short8_t*)&pP[pbase + j * 16 + lm][koff + 32];
                    float4_t accR;
#pragma unroll
                    for (int r = 0; r < 4; ++r) accR[r] = 0.f;
                    accR = __builtin_amdgcn_mfma_f32_16x16x32_bf16(aq[0], bp0, accR, 0, 0, 0);
                    accR = __builtin_amdgcn_mfma_f32_16x16x32_bf16(aq[1], bp1, accR, 0, 0, 0);
                    const int p = j * 16 + lm;
                    const float bv = biascp[h * NT + min(plo_w + p, NT - 1)];
#pragma unroll
                    for (int r = 0; r < 4; ++r) Rl[wave][quad * 4 + r][p] = accR[r] + bv;
                }
                asm volatile("" ::: "memory");   // order Rl write -> gather (same wave)

                // ---- e = exp((QK + R[t][t-s-plo_w]) / 9) * mask
#pragma unroll
                for (int j = 0; j < 4; ++j) {
                    const int s_g = s0 + j * 16 + lm;
#pragma unroll
                    for (int r = 0; r < 4; ++r) {
                        const int t_g = tw0 + quad * 4 + r;
                        float e = 0.f;
                        if (s_g <= t_g) {
                            const int p = t_g - s_g - plo_w;
                            e = __expf(fminf((accQK[j][r] + Rl[wave][quad * 4 + r][p]) * (1.f / 9.f), 60.f));
                        }
                        esl[wave][quad * 4 + r][j * 16 + lm] = f2b(e);
                        esum[r] += e;
                    }
                }
                asm volatile("" ::: "memory");   // order esl write -> A-frag read

                // ---- P.V: ctx[t][d] += e[t][s] * V[s][d]
                short8_t ae0 = *(const short8_t*)&esl[wave][lm][koff];
                short8_t ae1 = *(const short8_t*)&esl[wave][lm][koff + 32];
#pragma unroll
                for (int j = 0; j < 4; ++j) {
                    short8_t bv0 = *(const short8_t*)&Vt[j * 16 + lm][koff];
                    short8_t bv1 = *(const short8_t*)&Vt[j * 16 + lm][koff + 32];
                    ctxacc[j] = __builtin_amdgcn_mfma_f32_16x16x32_bf16(ae0, bv0, ctxacc[j], 0, 0, 0);
                    ctxacc[j] = __builtin_amdgcn_mfma_f32_16x16x32_bf16(ae1, bv1, ctxacc[j], 0, 0, 0);
                }
            }
        }

        // ---- per-tile epilogue: reduce esum within quad, normalize, store
        float rcpv[4];
#pragma unroll
        for (int r = 0; r < 4; ++r) {
            float v = esum[r];
            v += __shfl_xor(v, 1); v += __shfl_xor(v, 2);
            v += __shfl_xor(v, 4); v += __shfl_xor(v, 8);
            rcpv[r] = 1.f / (v + 2.f);
        }
#pragma unroll
        for (int j = 0; j < 4; ++j) {
            const int d = j * 16 + lm;
#pragma unroll
            for (int r = 0; r < 4; ++r) {
                const int t = tw0 + quad * 4 + r;
                ctxT[((size_t)(b * NT + t)) * ND + d * NH + h] = f2b(ctxacc[j][r] * rcpv[r]);
            }
        }
    }
}

extern "C" void kernel_launch(void* const* d_in, const int* in_sizes, int n_in,
                              void* d_out, int out_size, void* d_ws, size_t ws_size,
                              hipStream_t stream)
{
    const float* x    = (const float*)d_in[0];
    const float* rpe  = (const float*)d_in[1];
    const float* rcb  = (const float*)d_in[2];
    const float* rpb  = (const float*)d_in[3];
    const float* Wqkv = (const float*)d_in[4];
    const float* bqkv = (const float*)d_in[5];
    const float* Wh   = (const float*)d_in[6];
    const float* bh   = (const float*)d_in[7];
    const float* Wp   = (const float*)d_in[8];
    const float* bp   = (const float*)d_in[9];

    float* out  = (float*)d_out;             // (B,T,D) fp32
    float* kout = out + 3145728;             // (B,H,DH,T) fp32
    float* vout = out + 6291456;             // (B,H,T,DH) fp32

    unsigned short* q_ws  = (unsigned short*)d_ws;   // (B,H,T,DH) bf16
    unsigned short* k_ws  = q_ws + 3145728;          // (B,H,T,DH) bf16
    unsigned short* v_ws  = k_ws + 3145728;          // (B,H,DH,T) bf16
    unsigned short* ctxT  = v_ws + 3145728;          // (B,T,D) bf16  [= xb alias]
    unsigned short* xb    = ctxT;                    // x bf16 [4096][768] (pre-attn)
    unsigned short* projb = ctxT + 3145728;          // (H,P,DH) bf16
    float* biascp = (float*)(projb + 393216);        // (H,P) f32
    unsigned short* WqkvT = (unsigned short*)(biascp + 6144);  // [2304][768] bf16
    unsigned short* WhT   = WqkvT + 1769472;         // [768][768] bf16

    prep<<<dim3(3840), 256, 0, stream>>>(x, xb, Wqkv, WqkvT, Wh, WhT);

    gemm128<0><<<dim3(2304 / 128, 4096 / 128), 256, 0, stream>>>(
        xb, WqkvT, bqkv, q_ws, kout, vout, k_ws, v_ws, 768);
    gemm_proj<<<dim3(768 / 64, 512 / 64), 256, 0, stream>>>(
        rpe, Wp, bp, rcb, rpb, projb, biascp);
    attn_mfma<<<dim3(8, 96), 128, 0, stream>>>(
        q_ws, k_ws, v_ws, projb, biascp, ctxT);
    gemm128<2><<<dim3(768 / 128, 4096 / 128), 256, 0, stream>>>(
        ctxT, WhT, bh, nullptr, out, nullptr, nullptr, nullptr, 768);
}

// Round 7
// 205.996 us; speedup vs baseline: 1.9834x; 1.1602x over previous
//
#include <hip/hip_runtime.h>
#include <hip/hip_bf16.h>

// SelfMaskedAttention (Transformer-XL rel-pos), B=8 T=512 D=768 H=12 DH=64.
// R17: R16 resubmit (infra failure), hardened. GEMM tile 64x128 (acc[2][4]),
// QKV grid 1152 blocks (4.5/CU) + proj fused as 48 tail blocks w/ biascp
// epilogue; counted-vmcnt 3-deep loop. rpeb/WpT staged in d_out's dead first
// 12MB (ws back to ~29.3MB, below R12's proven 30.7MB). 4 dispatches.
// Attention (R13 paired-tile balance) unchanged.

#define NT 512
#define ND 768
#define NH 12

typedef short short4_t __attribute__((ext_vector_type(4)));
typedef short short8_t __attribute__((ext_vector_type(8)));
typedef float float4_t __attribute__((ext_vector_type(4)));

__device__ __forceinline__ float b2f(unsigned short u) {
    union { unsigned int i; float f; } x; x.i = ((unsigned int)u) << 16; return x.f;
}
__device__ __forceinline__ unsigned short f2b(float f) {
    union { float f; unsigned int i; } x; x.f = f;
    unsigned int i = x.i;
    i += 0x7fffu + ((i >> 16) & 1u);   // RNE
    return (unsigned short)(i >> 16);
}

// ---------------- fused pre-pass ----------------
// [0,1536): cvt x->xb; [1536,1728): cvt rpe->rpeb; [1728,3456): Wqkv^T;
// [3456,4032): Wh^T; [4032,4608): Wp^T. All bf16 outputs.
__global__ __launch_bounds__(256) void prep(
    const float* __restrict__ x, unsigned short* __restrict__ xb,
    const float* __restrict__ rpe, unsigned short* __restrict__ rpeb,
    const float* __restrict__ Wqkv, unsigned short* __restrict__ WqkvT,
    const float* __restrict__ Wh, unsigned short* __restrict__ WhT,
    const float* __restrict__ Wp, unsigned short* __restrict__ WpT)
{
    __shared__ float t[32][33];
    const int bid = blockIdx.x;
    const int tid = threadIdx.x;

    if (bid < 1728) {               // ---- cvt paths, 8 f32/thread
        const bool isx = bid < 1536;
        const float* in = isx ? x : rpe;
        unsigned short* out = isx ? xb : rpeb;
        const int i = (isx ? bid : bid - 1536) * 256 + tid;
        const float* s = in + (size_t)i * 8;
        float4_t f0 = *(const float4_t*)s;
        float4_t f1 = *(const float4_t*)(s + 4);
        union { short8_t v; unsigned short u[8]; } pk;
        pk.u[0] = f2b(f0[0]); pk.u[1] = f2b(f0[1]); pk.u[2] = f2b(f0[2]); pk.u[3] = f2b(f0[3]);
        pk.u[4] = f2b(f1[0]); pk.u[5] = f2b(f1[1]); pk.u[6] = f2b(f1[2]); pk.u[7] = f2b(f1[3]);
        *(short8_t*)&out[(size_t)i * 8] = pk.v;
        return;
    }
    // ---- transpose path: W [K][N] fp32 -> WT [N][K] bf16, 32x32 tile
    const float* in; unsigned short* out; int K, N, k0, n0;
    if (bid < 3456) {
        const int tt = bid - 1728;      // Wqkv: 72 n-tiles x 24 k-tiles
        in = Wqkv; out = WqkvT; K = 768; N = 2304;
        n0 = (tt % 72) * 32; k0 = (tt / 72) * 32;
    } else if (bid < 4032) {
        const int tt = bid - 3456;      // Wh: 24 x 24
        in = Wh; out = WhT; K = 768; N = 768;
        n0 = (tt % 24) * 32; k0 = (tt / 24) * 32;
    } else {
        const int tt = bid - 4032;      // Wp: 24 x 24
        in = Wp; out = WpT; K = 768; N = 768;
        n0 = (tt % 24) * 32; k0 = (tt / 24) * 32;
    }
    const int r = tid >> 3;
    const int c = (tid & 7) * 4;
    float4_t v = *(const float4_t*)&in[(size_t)(k0 + r) * N + n0 + c];
    t[r][c + 0] = v[0]; t[r][c + 1] = v[1]; t[r][c + 2] = v[2]; t[r][c + 3] = v[3];
    __syncthreads();
    union { short4_t v; unsigned short u[4]; } pk;
    pk.u[0] = f2b(t[c + 0][r]);
    pk.u[1] = f2b(t[c + 1][r]);
    pk.u[2] = f2b(t[c + 2][r]);
    pk.u[3] = f2b(t[c + 3][r]);
    *(short4_t*)&out[(size_t)(n0 + r) * K + k0 + c] = pk.v;
}

// ---------------- 64x128-tile MFMA GEMM, 3-deep counted-vmcnt pipeline -------
// A [M][K] bf16, BT [N][K] bf16 row-major. 256 thr = 4 waves (2x2 over
// 32x64 quadrants), acc[2][4], BK=32, 3 global_load_lds/step (A:1, B:2).
// MODE 0: blocks [0,1152) = QKV (M=4096,N=2304); [1152,1200) = proj GEMM
// (rpeb @ WpT, M=512,N=768) with projb + biascp epilogue. MODE 2: out GEMM.
template <int MODE>
__global__ __launch_bounds__(256) void gemm64(
    const unsigned short* __restrict__ A, const unsigned short* __restrict__ BT,
    const float* __restrict__ biasf,
    unsigned short* __restrict__ ob0, float* __restrict__ o1, float* __restrict__ o2,
    unsigned short* __restrict__ sh1, unsigned short* __restrict__ sh2,
    const unsigned short* __restrict__ Ap, const unsigned short* __restrict__ BTp,
    const float* __restrict__ biasp, const float* __restrict__ rcb,
    const float* __restrict__ rpb, unsigned short* __restrict__ projb,
    float* __restrict__ biascp)
{
    __shared__ __attribute__((aligned(16))) unsigned short Al[3][64 * 32];
    __shared__ __attribute__((aligned(16))) unsigned short Bl[3][128 * 32];

    const int K    = 768;
    const int tid  = threadIdx.x;
    const int bid  = blockIdx.x;
    const int wave = tid >> 6;
    const int lane = tid & 63;
    const int lm   = lane & 15;
    const int quad = lane >> 4;
    const int wr   = (wave >> 1) * 32;   // wave row offset (2 rows of waves)
    const int wc   = (wave & 1) * 64;    // wave col offset (2 cols of waves)

    int m0, n0; bool proj = false;
    const unsigned short *Asrc, *Bsrc;
    if (MODE == 0) {
        if (bid < 1152) { m0 = (bid / 18) * 64; n0 = (bid % 18) * 128; Asrc = A;  Bsrc = BT; }
        else { const int pb = bid - 1152; m0 = (pb / 6) * 64; n0 = (pb % 6) * 128;
               Asrc = Ap; Bsrc = BTp; proj = true; }
    } else {
        m0 = (bid / 6) * 64; n0 = (bid % 6) * 128; Asrc = A; Bsrc = BT;
    }

    float4_t acc[2][4];
#pragma unroll
    for (int mt = 0; mt < 2; ++mt)
#pragma unroll
        for (int nt = 0; nt < 4; ++nt)
#pragma unroll
            for (int r = 0; r < 4; ++r) acc[mt][nt][r] = 0.f;

    const unsigned short* ap = Asrc + (size_t)(m0 + (tid >> 2)) * K + (tid & 3) * 8;
    const unsigned short* bp = Bsrc + (size_t)(n0 + (tid >> 2)) * K + (tid & 3) * 8;
    const size_t rstep = (size_t)64 * K;

    auto stage = [&](int bi, int k0) {
        unsigned short* al0 = &Al[bi][0] + wave * 512;   // 1KB/wave, A 4KB total
        unsigned short* bl0 = &Bl[bi][0] + wave * 512;   // B 8KB: 2 issues
        __builtin_amdgcn_global_load_lds(
            (const __attribute__((address_space(1))) void*)(ap + k0),
            (__attribute__((address_space(3))) void*)al0, 16, 0, 0);
        __builtin_amdgcn_global_load_lds(
            (const __attribute__((address_space(1))) void*)(bp + k0),
            (__attribute__((address_space(3))) void*)bl0, 16, 0, 0);
        __builtin_amdgcn_global_load_lds(
            (const __attribute__((address_space(1))) void*)(bp + rstep + k0),
            (__attribute__((address_space(3))) void*)(bl0 + 2048), 16, 0, 0);
    };

    stage(0, 0);
    stage(1, 32);

    int cur = 0;
    for (int k0 = 0; k0 < K; k0 += 32) {
        if (k0 + 32 < K) asm volatile("s_waitcnt vmcnt(3)" ::: "memory");
        else             asm volatile("s_waitcnt vmcnt(0)" ::: "memory");
        __builtin_amdgcn_s_barrier();
        __builtin_amdgcn_sched_barrier(0);

        if (k0 + 64 < K) stage((cur + 2) % 3, k0 + 64);

        short8_t af[2], bf[4];
#pragma unroll
        for (int mt = 0; mt < 2; ++mt)
            af[mt] = *(const short8_t*)&Al[cur][(wr + mt * 16 + lm) * 32 + quad * 8];
#pragma unroll
        for (int nt = 0; nt < 4; ++nt)
            bf[nt] = *(const short8_t*)&Bl[cur][(wc + nt * 16 + lm) * 32 + quad * 8];
#pragma unroll
        for (int mt = 0; mt < 2; ++mt)
#pragma unroll
            for (int nt = 0; nt < 4; ++nt)
                acc[mt][nt] = __builtin_amdgcn_mfma_f32_16x16x32_bf16(af[mt], bf[nt], acc[mt][nt], 0, 0, 0);

        cur = (cur + 1) % 3;
    }

    if (MODE == 2) {
#pragma unroll
        for (int nt = 0; nt < 4; ++nt) {
            const int gcol = n0 + wc + nt * 16 + lm;
            const float bv = biasf[gcol];
#pragma unroll
            for (int mt = 0; mt < 2; ++mt)
#pragma unroll
                for (int r = 0; r < 4; ++r) {
                    const int grow = m0 + wr + mt * 16 + quad * 4 + r;
                    o1[(size_t)grow * ND + gcol] = acc[mt][nt][r] + bv;
                }
        }
        return;
    }

    if (!proj) {
        const int sec = n0 / 768;          // block-uniform (128 | 768)
#pragma unroll
        for (int nt = 0; nt < 4; ++nt) {
            const int gcol = n0 + wc + nt * 16 + lm;
            const int cc = gcol - sec * 768;
            const int h = cc >> 6, d = cc & 63;
            const float bv = biasf[gcol];
#pragma unroll
            for (int mt = 0; mt < 2; ++mt)
#pragma unroll
                for (int r = 0; r < 4; ++r) {
                    const int grow = m0 + wr + mt * 16 + quad * 4 + r;
                    const int b = grow >> 9, t = grow & 511;
                    const float val = acc[mt][nt][r] + bv;
                    if (sec == 0) {
                        ob0[((size_t)((b * NH + h) * NT + t)) * 64 + d] = f2b(val);
                    } else if (sec == 1) {
                        o1[((size_t)((b * NH + h) * 64 + d)) * NT + t] = val;
                        sh1[((size_t)((b * NH + h) * NT + t)) * 64 + d] = f2b(val);
                    } else {
                        o2[((size_t)((b * NH + h) * NT + t)) * 64 + d] = val;
                        sh2[((size_t)((b * NH + h) * 64 + d)) * NT + t] = f2b(val);
                    }
                }
        }
    } else {
        const int h = (n0 + wc) >> 6;      // wave spans exactly one head
        float part[2][4];
#pragma unroll
        for (int mt = 0; mt < 2; ++mt)
#pragma unroll
            for (int r = 0; r < 4; ++r) part[mt][r] = 0.f;
#pragma unroll
        for (int nt = 0; nt < 4; ++nt) {
            const int gcol = n0 + wc + nt * 16 + lm;
            const int d = gcol & 63;
            const float bv = biasp[gcol];
            const float cb = rcb[h * 64 + d] + rpb[h * 64 + d];
#pragma unroll
            for (int mt = 0; mt < 2; ++mt)
#pragma unroll
                for (int r = 0; r < 4; ++r) {
                    const int grow = m0 + wr + mt * 16 + quad * 4 + r;
                    const float val = acc[mt][nt][r] + bv;
                    projb[((size_t)(h * NT + grow)) * 64 + d] = f2b(val);
                    part[mt][r] += val * cb;
                }
        }
#pragma unroll
        for (int mt = 0; mt < 2; ++mt)
#pragma unroll
            for (int r = 0; r < 4; ++r) {
                float v = part[mt][r];
                v += __shfl_xor(v, 1); v += __shfl_xor(v, 2);
                v += __shfl_xor(v, 4); v += __shfl_xor(v, 8);
                if (lm == 0)
                    biascp[h * NT + m0 + wr + mt * 16 + quad * 4 + r] = v;
            }
    }
}

// ---------------- MFMA attention: grid (8, 96), 128 thr, paired 32-row tiles --
__global__ __launch_bounds__(128) void attn_mfma(
    const unsigned short* __restrict__ q_ws, const unsigned short* __restrict__ k_ws,
    const unsigned short* __restrict__ v_ws, const unsigned short* __restrict__ projb,
    const float* __restrict__ biascp, unsigned short* __restrict__ ctxT)
{
    __shared__ unsigned short Kt[64][72];    // [s][d] bf16
    __shared__ unsigned short Vt[64][72];    // [d][s] bf16
    __shared__ unsigned short pP[96][72];    // [p][d] bf16 (tile rel-window)
    __shared__ float          Rl[2][16][84]; // per-wave R + bias, f32
    __shared__ unsigned short esl[2][16][72];// per-wave e bf16 (PV A-operand)

    const int tid   = threadIdx.x;
    const int y     = blockIdx.y;       // b*H + h
    const int h     = y % NH;
    const int b     = y / NH;
    const int pairi = blockIdx.x;       // 0..7
    const int wave  = tid >> 6;
    const int lane  = tid & 63;
    const int lm    = lane & 15;
    const int quad  = lane >> 4;
    const int koff  = quad * 8;

    const int sr = tid >> 1;           // staging row 0..63
    const int sc = (tid & 1) * 32;     // 32-short chunk

    for (int c = 0; c < 2; ++c) {
        const int ti  = c ? pairi : (15 - pairi);
        const int tb0 = ti * 32;
        const int tw0 = tb0 + wave * 16;
        const int nst = (tb0 >> 6) + 1;

        short8_t aq[2];
        aq[0] = *(const short8_t*)&q_ws[((size_t)(y * NT + tw0 + lm)) * 64 + koff];
        aq[1] = *(const short8_t*)&q_ws[((size_t)(y * NT + tw0 + lm)) * 64 + koff + 32];

        float4_t ctxacc[4];
#pragma unroll
        for (int j = 0; j < 4; ++j)
#pragma unroll
            for (int r = 0; r < 4; ++r) ctxacc[j][r] = 0.f;
        float esum[4] = {0.f, 0.f, 0.f, 0.f};

        for (int st = 0; st < nst; ++st) {
            const int s0      = st * 64;
            const int plo_blk = max(0, tb0 - s0 - 63);
            const int cnt_blk = tb0 + 31 - s0 - plo_blk + 1;   // 32..95
            if (c | st) __syncthreads();
            {   // ---- stage K^T [s][d], V^T [d][s], proj window — short8 copies
                const unsigned short* ks = &k_ws[((size_t)(y * NT + s0 + sr)) * 64 + sc];
                *(short8_t*)&Kt[sr][sc]      = *(const short8_t*)ks;
                *(short8_t*)&Kt[sr][sc + 8]  = *(const short8_t*)(ks + 8);
                *(short8_t*)&Kt[sr][sc + 16] = *(const short8_t*)(ks + 16);
                *(short8_t*)&Kt[sr][sc + 24] = *(const short8_t*)(ks + 24);
                const unsigned short* vs = &v_ws[((size_t)(y * 64 + sr)) * NT + s0 + sc];
                *(short8_t*)&Vt[sr][sc]      = *(const short8_t*)vs;
                *(short8_t*)&Vt[sr][sc + 8]  = *(const short8_t*)(vs + 8);
                *(short8_t*)&Vt[sr][sc + 16] = *(const short8_t*)(vs + 16);
                *(short8_t*)&Vt[sr][sc + 24] = *(const short8_t*)(vs + 24);
                for (int p = tid; p < cnt_blk; p += 128) {
                    const unsigned short* ps = &projb[((size_t)(h * NT + plo_blk + p)) * 64];
                    *(short8_t*)&pP[p][0]  = *(const short8_t*)ps;
                    *(short8_t*)&pP[p][8]  = *(const short8_t*)(ps + 8);
                    *(short8_t*)&pP[p][16] = *(const short8_t*)(ps + 16);
                    *(short8_t*)&pP[p][24] = *(const short8_t*)(ps + 24);
                    *(short8_t*)&pP[p][32] = *(const short8_t*)(ps + 32);
                    *(short8_t*)&pP[p][40] = *(const short8_t*)(ps + 40);
                    *(short8_t*)&pP[p][48] = *(const short8_t*)(ps + 48);
                    *(short8_t*)&pP[p][56] = *(const short8_t*)(ps + 56);
                }
            }
            __syncthreads();

            if (s0 <= tw0 + 15) {   // wave-uniform: wave has active s here
                const int plo_w = max(0, tw0 - s0 - 63);
                const int pbase = plo_w - plo_blk;            // 0 or 16
                const int cntw  = tw0 + 15 - s0 - plo_w + 1;  // 16..79
                const int jmax  = min(3, (tw0 + 15 - s0) >> 4);
                const int jpmax = (cntw - 1) >> 4;            // <= 4

                // ---- QK^T
                float4_t accQK[4];
#pragma unroll
                for (int j = 0; j < 4; ++j)
#pragma unroll
                    for (int r = 0; r < 4; ++r) accQK[j][r] = 0.f;
                for (int j = 0; j <= jmax; ++j) {
                    short8_t bk0 = *(const short8_t*)&Kt[j * 16 + lm][koff];
                    short8_t bk1 = *(const short8_t*)&Kt[j * 16 + lm][koff + 32];
                    accQK[j] = __builtin_amdgcn_mfma_f32_16x16x32_bf16(aq[0], bk0, accQK[j], 0, 0, 0);
                    accQK[j] = __builtin_amdgcn_mfma_f32_16x16x32_bf16(aq[1], bk1, accQK[j], 0, 0, 0);
                }
                // ---- R = Q . proj^T, bias folded at write
                for (int j = 0; j <= jpmax; ++j) {
                    short8_t bp0 = *(const short8_t*)&pP[pbase + j * 16 + lm][koff];
                    short8_t bp1 = *(const short8_t*)&pP[pbase + j * 16 + lm][koff + 32];
                    float4_t accR;
#pragma unroll
                    for (int r = 0; r < 4; ++r) accR[r] = 0.f;
                    accR = __builtin_amdgcn_mfma_f32_16x16x32_bf16(aq[0], bp0, accR, 0, 0, 0);
                    accR = __builtin_amdgcn_mfma_f32_16x16x32_bf16(aq[1], bp1, accR, 0, 0, 0);
                    const int p = j * 16 + lm;
                    const float bv = biascp[h * NT + min(plo_w + p, NT - 1)];
#pragma unroll
                    for (int r = 0; r < 4; ++r) Rl[wave][quad * 4 + r][p] = accR[r] + bv;
                }
                asm volatile("" ::: "memory");   // order Rl write -> gather (same wave)

                // ---- e = exp((QK + R[t][t-s-plo_w]) / 9) * mask
#pragma unroll
                for (int j = 0; j < 4; ++j) {
                    const int s_g = s0 + j * 16 + lm;
#pragma unroll
                    for (int r = 0; r < 4; ++r) {
                        const int t_g = tw0 + quad * 4 + r;
                        float e = 0.f;
                        if (s_g <= t_g) {
                            const int p = t_g - s_g - plo_w;
                            e = __expf(fminf((accQK[j][r] + Rl[wave][quad * 4 + r][p]) * (1.f / 9.f), 60.f));
                        }
                        esl[wave][quad * 4 + r][j * 16 + lm] = f2b(e);
                        esum[r] += e;
                    }
                }
                asm volatile("" ::: "memory");   // order esl write -> A-frag read

                // ---- P.V: ctx[t][d] += e[t][s] * V[s][d]
                short8_t ae0 = *(const short8_t*)&esl[wave][lm][koff];
                short8_t ae1 = *(const short8_t*)&esl[wave][lm][koff + 32];
#pragma unroll
                for (int j = 0; j < 4; ++j) {
                    short8_t bv0 = *(const short8_t*)&Vt[j * 16 + lm][koff];
                    short8_t bv1 = *(const short8_t*)&Vt[j * 16 + lm][koff + 32];
                    ctxacc[j] = __builtin_amdgcn_mfma_f32_16x16x32_bf16(ae0, bv0, ctxacc[j], 0, 0, 0);
                    ctxacc[j] = __builtin_amdgcn_mfma_f32_16x16x32_bf16(ae1, bv1, ctxacc[j], 0, 0, 0);
                }
            }
        }

        // ---- per-tile epilogue: reduce esum within quad, normalize, store
        float rcpv[4];
#pragma unroll
        for (int r = 0; r < 4; ++r) {
            float v = esum[r];
            v += __shfl_xor(v, 1); v += __shfl_xor(v, 2);
            v += __shfl_xor(v, 4); v += __shfl_xor(v, 8);
            rcpv[r] = 1.f / (v + 2.f);
        }
#pragma unroll
        for (int j = 0; j < 4; ++j) {
            const int d = j * 16 + lm;
#pragma unroll
            for (int r = 0; r < 4; ++r) {
                const int t = tw0 + quad * 4 + r;
                ctxT[((size_t)(b * NT + t)) * ND + d * NH + h] = f2b(ctxacc[j][r] * rcpv[r]);
            }
        }
    }
}

extern "C" void kernel_launch(void* const* d_in, const int* in_sizes, int n_in,
                              void* d_out, int out_size, void* d_ws, size_t ws_size,
                              hipStream_t stream)
{
    const float* x    = (const float*)d_in[0];
    const float* rpe  = (const float*)d_in[1];
    const float* rcb  = (const float*)d_in[2];
    const float* rpb  = (const float*)d_in[3];
    const float* Wqkv = (const float*)d_in[4];
    const float* bqkv = (const float*)d_in[5];
    const float* Wh   = (const float*)d_in[6];
    const float* bh   = (const float*)d_in[7];
    const float* Wp   = (const float*)d_in[8];
    const float* bp   = (const float*)d_in[9];

    float* out  = (float*)d_out;             // (B,T,D) fp32
    float* kout = out + 3145728;             // (B,H,DH,T) fp32
    float* vout = out + 6291456;             // (B,H,T,DH) fp32

    unsigned short* q_ws  = (unsigned short*)d_ws;   // (B,H,T,DH) bf16
    unsigned short* k_ws  = q_ws + 3145728;          // (B,H,T,DH) bf16
    unsigned short* v_ws  = k_ws + 3145728;          // (B,H,DH,T) bf16
    unsigned short* ctxT  = v_ws + 3145728;          // (B,T,D) bf16  [= xb alias]
    unsigned short* xb    = ctxT;                    // x bf16 (pre-attn live range)
    unsigned short* projb = ctxT + 3145728;          // (H,P,DH) bf16
    float* biascp = (float*)(projb + 393216);        // (H,P) f32
    unsigned short* WqkvT = (unsigned short*)(biascp + 6144);  // [2304][768] bf16
    unsigned short* WhT   = WqkvT + 1769472;         // [768][768] bf16 — ws ~29.3 MB
    // rpeb/WpT live in d_out's first 12MB (dead until gemm64<2> writes out;
    // both are consumed before that dispatch). WhT must NOT go here (gemm64<2>
    // reads it while writing out).
    unsigned short* rpeb  = (unsigned short*)out;    // [512][768] bf16
    unsigned short* WpT   = rpeb + 393216;           // [768][768] bf16

    prep<<<dim3(4608), 256, 0, stream>>>(x, xb, rpe, rpeb, Wqkv, WqkvT, Wh, WhT, Wp, WpT);

    gemm64<0><<<dim3(1200), 256, 0, stream>>>(
        xb, WqkvT, bqkv, q_ws, kout, vout, k_ws, v_ws,
        rpeb, WpT, bp, rcb, rpb, projb, biascp);
    attn_mfma<<<dim3(8, 96), 128, 0, stream>>>(
        q_ws, k_ws, v_ws, projb, biascp, ctxT);
    gemm64<2><<<dim3(384), 256, 0, stream>>>(
        ctxT, WhT, bh, nullptr, out, nullptr, nullptr, nullptr,
        nullptr, nullptr, nullptr, nullptr, nullptr, nullptr, nullptr);
}